// Round 8
// baseline (926.382 us; speedup 1.0000x reference)
//
#include <hip/hip_runtime.h>

// ---------------------------------------------------------------------------
// Hetero GraphSAGE (2 layers) + edge decoder.
// R1: CSR-gather aggregation. R4: algebraic restructure. R5: bf16 MFMA GEMMs.
// R6: fp16 U/V. R8: two-pass LDS-binned CSR fill. R10: XCD-paired swizzle.
// R12: 512-thread mgemm, 32x64 wave tile (proven 74.5us NS-GEMM).
// R13/R14: W-in-LDS GEMM — REGRESSED 2x, reverted.
// R15: fused dispatches ([GEMM||gather], [GEMM||GEMM], [cvt||count]).
// R16-R19: cvt restructures (grid-stride, ILP-4) — NO CHANGE, 108-113us
//   regardless of cvt code. Inference: the COUNT half (1.6M scattered
//   device atomics) is the dispatch floor; cvt hides under it. Baseline's
//   SEPARATE cvt/count kernels were each <74us — the fusion itself regressed.
// R20 (this): unfuse. count_kernel (ILP-4 loads, 782 blocks) + cvt_kernel
//   (R18 chunked ILP-4, 2048 blocks) as separate dispatches. Measures each
//   standalone; if count alone is ~90us+, next round does LDS-binned count.
// ---------------------------------------------------------------------------

constexpr int NS = 100000, NT = 20000;
constexpr int E_EDGES = 800000, EL_EDGES = 200000;
constexpr int DS = 256, DT = 128, H = 256;

constexpr int NB_T = 79, SH_T = 8, VB_T = 17;
constexpr int NB_S = 98, SH_S = 10, VB_S = 15;
constexpr int BIN_CAP = 96, CHUNK = 2048;
constexpr int CVT_BLOCKS = 2048;

typedef __attribute__((ext_vector_type(8))) short short8;
typedef __attribute__((ext_vector_type(4))) float float4v;
typedef __attribute__((ext_vector_type(8))) _Float16 half8v;
typedef unsigned short ushort_t;

__device__ __forceinline__ float bf2f(unsigned int u) {
    union { unsigned int i; float f; } x; x.i = u << 16; return x.f;
}
__device__ __forceinline__ unsigned short f2bf(float f) {
    union { float f; unsigned int i; } x; x.f = f;
    unsigned int r = x.i + 0x7FFFu + ((x.i >> 16) & 1u);   // RNE
    return (unsigned short)(r >> 16);
}

// --------------------------- MFMA GEMM body (R12, proven) ------------------
// C[M,256] = op( A1@W1^T [+ A2@W2^T] [+ Add] [+ bias] )
// 128x128 block tile, BK=32, LDS stride 40, XCD-paired swizzle, reg prefetch.
// 512 threads / 8 waves; wave (g=wave>>1, h=wave&1) owns rows
// [32g,32g+32) x cols [64h,64h+64): acc[2][4], 32 AGPR/wave.
// flags: 1 = relu, 2 = fp16 output (else bf16)

struct GemmJob {
    const ushort_t* A1; const ushort_t* W1; int K1;
    const ushort_t* A2; const ushort_t* W2; int K2;
    const ushort_t* Add; const float* bias;
    void* C; int M; int flags;
};

struct GatherJob {
    const ushort_t* X; const int* rowptr; const int* cnt; const int* col;
    ushort_t* out; int N;
};

__device__ __forceinline__ void gemm_body(const GemmJob& jb, int bid)
{
    __shared__ ushort_t As[128][40];
    __shared__ ushort_t Bs[128][40];
    const int tid = threadIdx.x;
    const int M = jb.M;

    // ---- XCD-paired swizzle: bid -> (rowblk, colblk) ----
    const int nx = (M + 127) >> 7;          // row-blocks
    const int nx8 = nx & ~7;                // swizzled region (multiple of 8)
    int rowblk, colblk;
    if (bid < nx8 * 2) {
        const int group = bid >> 4;         // 16 blocks per group
        const int xcd = bid & 7;
        const int half = (bid >> 3) & 1;
        rowblk = group * 8 + xcd;
        colblk = half;
    } else {
        const int r = bid - nx8 * 2;
        rowblk = nx8 + (r >> 1);
        colblk = r & 1;
    }
    const int row0 = rowblk * 128, col0 = colblk * 128;

    const int wave = tid >> 6, lane = tid & 63;
    const int wrow = (wave >> 1) * 32;      // 4 row-groups of 32
    const int wcol = (wave & 1) * 64;       // 2 col-groups of 64
    const int m16 = lane & 15, quad = lane >> 4;
    const int sr = tid >> 2;                // staging row 0..127
    const int skc = (tid & 3) * 8;          // k-chunk (ushorts): 0,8,16,24

    float4v acc[2][4];
#pragma unroll
    for (int i = 0; i < 2; i++)
#pragma unroll
        for (int j = 0; j < 4; j++) acc[i][j] = (float4v){0.f, 0.f, 0.f, 0.f};

#pragma unroll 1
    for (int pass = 0; pass < 2; pass++) {
        const ushort_t* A = pass ? jb.A2 : jb.A1;
        const ushort_t* W = pass ? jb.W2 : jb.W1;
        const int K = pass ? jb.K2 : jb.K1;
        if (!A) break;
        const int gra = row0 + sr;
        const bool oka = gra < M;
        const ushort_t* Ap = A + (size_t)gra * K + skc;
        const ushort_t* Wp = W + (size_t)(col0 + sr) * K + skc;

        // preload tile 0
        uint4 a0 = make_uint4(0, 0, 0, 0);
        if (oka) a0 = *(const uint4*)Ap;
        uint4 b0 = *(const uint4*)Wp;

        for (int k0 = 0; k0 < K; k0 += 32) {
            __syncthreads();                 // prev iter done reading LDS
            *(uint4*)&As[sr][skc] = a0;
            *(uint4*)&Bs[sr][skc] = b0;
            __syncthreads();                 // LDS ready
            if (k0 + 32 < K) {               // prefetch tile k+1
                a0 = make_uint4(0, 0, 0, 0);
                if (oka) a0 = *(const uint4*)(Ap + k0 + 32);
                b0 = *(const uint4*)(Wp + k0 + 32);
            }
            short8 af[2], bf[4];
#pragma unroll
            for (int i = 0; i < 2; i++)
                af[i] = *(const short8*)&As[wrow + i * 16 + m16][quad * 8];
#pragma unroll
            for (int j = 0; j < 4; j++)
                bf[j] = *(const short8*)&Bs[wcol + j * 16 + m16][quad * 8];
#pragma unroll
            for (int i = 0; i < 2; i++)
#pragma unroll
                for (int j = 0; j < 4; j++)
                    acc[i][j] = __builtin_amdgcn_mfma_f32_16x16x32_bf16(
                        af[i], bf[j], acc[i][j], 0, 0, 0);
        }
    }

    const bool relu = jb.flags & 1, f16out = jb.flags & 2;
#pragma unroll
    for (int i = 0; i < 2; i++) {
        const int rbase = row0 + wrow + i * 16 + quad * 4;
#pragma unroll
        for (int r = 0; r < 4; r++) {
            const int row = rbase + r;
            if (row >= M) continue;
#pragma unroll
            for (int j = 0; j < 4; j++) {
                const int col = col0 + wcol + j * 16 + m16;
                float v = acc[i][j][r];
                if (jb.Add) v += bf2f((unsigned int)jb.Add[(size_t)row * 256 + col]);
                if (jb.bias) v += jb.bias[col];
                if (relu) v = fmaxf(v, 0.f);
                if (f16out) ((_Float16*)jb.C)[(size_t)row * 256 + col] = (_Float16)v;
                else ((ushort_t*)jb.C)[(size_t)row * 256 + col] = f2bf(v);
            }
        }
    }
}

// ---------------- gather mean body (bf16 rows, fp32 accum) -----------------
// 512 threads: 16 nodes/block, 32 lanes per node (8 cols each).
__device__ __forceinline__ void gather_body(const GatherJob& g, int gb)
{
    const int node = gb * 16 + (threadIdx.x >> 5);
    const int c = (threadIdx.x & 31) * 8;
    if (node >= g.N) return;
    const int beg = g.rowptr[node];
    const int deg = g.cnt[node];
    const int end = beg + deg;
    const ushort_t* __restrict__ X = g.X;
    const int* __restrict__ col = g.col;
    float a[8] = {0, 0, 0, 0, 0, 0, 0, 0};
    float b[8] = {0, 0, 0, 0, 0, 0, 0, 0};
    int i = beg;
    for (; i + 1 < end; i += 2) {
        uint4 v = *(const uint4*)&X[(size_t)col[i] * 256 + c];
        uint4 w = *(const uint4*)&X[(size_t)col[i + 1] * 256 + c];
        a[0] += bf2f(v.x & 0xffff); a[1] += bf2f(v.x >> 16);
        a[2] += bf2f(v.y & 0xffff); a[3] += bf2f(v.y >> 16);
        a[4] += bf2f(v.z & 0xffff); a[5] += bf2f(v.z >> 16);
        a[6] += bf2f(v.w & 0xffff); a[7] += bf2f(v.w >> 16);
        b[0] += bf2f(w.x & 0xffff); b[1] += bf2f(w.x >> 16);
        b[2] += bf2f(w.y & 0xffff); b[3] += bf2f(w.y >> 16);
        b[4] += bf2f(w.z & 0xffff); b[5] += bf2f(w.z >> 16);
        b[6] += bf2f(w.w & 0xffff); b[7] += bf2f(w.w >> 16);
    }
    if (i < end) {
        uint4 v = *(const uint4*)&X[(size_t)col[i] * 256 + c];
        a[0] += bf2f(v.x & 0xffff); a[1] += bf2f(v.x >> 16);
        a[2] += bf2f(v.y & 0xffff); a[3] += bf2f(v.y >> 16);
        a[4] += bf2f(v.z & 0xffff); a[5] += bf2f(v.z >> 16);
        a[6] += bf2f(v.w & 0xffff); a[7] += bf2f(v.w >> 16);
    }
    float inv = 1.f / fmaxf((float)deg, 1.f);
    uint4 o;
    o.x = (unsigned int)f2bf((a[0] + b[0]) * inv) | ((unsigned int)f2bf((a[1] + b[1]) * inv) << 16);
    o.y = (unsigned int)f2bf((a[2] + b[2]) * inv) | ((unsigned int)f2bf((a[3] + b[3]) * inv) << 16);
    o.z = (unsigned int)f2bf((a[4] + b[4]) * inv) | ((unsigned int)f2bf((a[5] + b[5]) * inv) << 16);
    o.w = (unsigned int)f2bf((a[6] + b[6]) * inv) | ((unsigned int)f2bf((a[7] + b[7]) * inv) << 16);
    *(uint4*)&g.out[(size_t)node * 256 + c] = o;
}

// --------------------------- fused launch shells ---------------------------
__global__ __launch_bounds__(512) void mgemm_kernel(GemmJob a)
{
    gemm_body(a, blockIdx.x);
}

__global__ __launch_bounds__(512) void gemm_gather_kernel(GemmJob a, int ablocks,
                                                          GatherJob g)
{
    const int bid = blockIdx.x;
    if (bid < ablocks) gemm_body(a, bid);
    else gather_body(g, bid - ablocks);
}

__global__ __launch_bounds__(512) void gemm_gemm_kernel(GemmJob a, int ablocks,
                                                        GemmJob b)
{
    const int bid = blockIdx.x;
    if (bid < ablocks) gemm_body(a, bid);
    else gemm_body(b, bid - ablocks);
}

// ----------------------- ILP-4 fp32 -> bf16 convert ------------------------
// Every job's float4-count is a multiple of 1024, so a 1024-float4 chunk
// never spans a job boundary: one uniform job-search per chunk, then each
// thread issues 4 independent coalesced loads (t, t+256, t+512, t+768).
struct CvtJobs {
    const float* src[14];
    ushort_t* dst[14];
    int n4[14];
    int cnt;
};

__global__ __launch_bounds__(256) void cvt_kernel(CvtJobs jb, int nchunks)
{
    const int t = threadIdx.x;
#pragma unroll 1
    for (int ch = blockIdx.x; ch < nchunks; ch += gridDim.x) {
        int idx = ch << 10;                // first float4 of this chunk
        int k = 0;
        while (idx >= jb.n4[k]) { idx -= jb.n4[k]; ++k; }   // uniform search
        const float4* __restrict__ s = (const float4*)jb.src[k];
        ushort_t* __restrict__ d = jb.dst[k];
        const int base = idx + t;
        // 4 independent loads in flight before any use
        float4 v0 = s[base];
        float4 v1 = s[base + 256];
        float4 v2 = s[base + 512];
        float4 v3 = s[base + 768];
        uint2 o0, o1, o2, o3;
        o0.x = (unsigned int)f2bf(v0.x) | ((unsigned int)f2bf(v0.y) << 16);
        o0.y = (unsigned int)f2bf(v0.z) | ((unsigned int)f2bf(v0.w) << 16);
        o1.x = (unsigned int)f2bf(v1.x) | ((unsigned int)f2bf(v1.y) << 16);
        o1.y = (unsigned int)f2bf(v1.z) | ((unsigned int)f2bf(v1.w) << 16);
        o2.x = (unsigned int)f2bf(v2.x) | ((unsigned int)f2bf(v2.y) << 16);
        o2.y = (unsigned int)f2bf(v2.z) | ((unsigned int)f2bf(v2.w) << 16);
        o3.x = (unsigned int)f2bf(v3.x) | ((unsigned int)f2bf(v3.y) << 16);
        o3.y = (unsigned int)f2bf(v3.z) | ((unsigned int)f2bf(v3.w) << 16);
        *(uint2*)(d + (size_t)base * 4) = o0;
        *(uint2*)(d + (size_t)(base + 256) * 4) = o1;
        *(uint2*)(d + (size_t)(base + 512) * 4) = o2;
        *(uint2*)(d + (size_t)(base + 768) * 4) = o3;
    }
}

// ----------------------- edge-degree count (ILP-4) -------------------------
__global__ __launch_bounds__(256) void count_kernel(
    const int* __restrict__ src, const int* __restrict__ dst,
    int* __restrict__ cnt_s, int* __restrict__ cnt_t, int E)
{
    const int base = blockIdx.x * 1024 + threadIdx.x;
    const int e0 = base, e1 = base + 256, e2 = base + 512, e3 = base + 768;
    int s0 = 0, s1 = 0, s2 = 0, s3 = 0;
    int d0 = 0, d1 = 0, d2 = 0, d3 = 0;
    if (e0 < E) { s0 = src[e0]; d0 = dst[e0]; }
    if (e1 < E) { s1 = src[e1]; d1 = dst[e1]; }
    if (e2 < E) { s2 = src[e2]; d2 = dst[e2]; }
    if (e3 < E) { s3 = src[e3]; d3 = dst[e3]; }
    if (e0 < E) { atomicAdd(&cnt_s[s0], 1); atomicAdd(&cnt_t[d0], 1); }
    if (e1 < E) { atomicAdd(&cnt_s[s1], 1); atomicAdd(&cnt_t[d1], 1); }
    if (e2 < E) { atomicAdd(&cnt_s[s2], 1); atomicAdd(&cnt_t[d2], 1); }
    if (e3 < E) { atomicAdd(&cnt_s[s3], 1); atomicAdd(&cnt_t[d3], 1); }
}

// -------------- decoder weight folding (one fused kernel) ------------------
__global__ __launch_bounds__(256) void fold_kernel(
    const float* __restrict__ Wd1, const float* __restrict__ bd1,
    const float* __restrict__ Wlin_s, const float* __restrict__ blin_s,
    const float* __restrict__ Wlin_t, const float* __restrict__ blin_t,
    float* __restrict__ Wc_s, float* __restrict__ Wc_t,
    float* __restrict__ bu, float* __restrict__ bv)
{
    const int b = blockIdx.x, t = threadIdx.x;
    if (b < 256) {
        float s = 0.f;
        for (int k = 0; k < 256; k++) s += Wd1[b * 512 + k] * Wlin_s[k * 256 + t];
        Wc_s[b * 256 + t] = s;
    } else if (b < 512) {
        const int h = b - 256;
        float s = 0.f;
        for (int k = 0; k < 256; k++) s += Wd1[h * 512 + 256 + k] * Wlin_t[k * 256 + t];
        Wc_t[h * 256 + t] = s;
    } else {
        float su = 0.f, sv = 0.f;
        for (int k = 0; k < 256; k++) {
            su += Wd1[t * 512 + k] * blin_s[k];
            sv += Wd1[t * 512 + 256 + k] * blin_t[k];
        }
        bu[t] = bd1[t] + su;
        bv[t] = sv;
    }
}

// --------------------------- CSR build -------------------------------------
__global__ __launch_bounds__(256) void psum_kernel(
    const int* __restrict__ cnt_s, const int* __restrict__ cnt_t,
    int* __restrict__ bsum_s, int* __restrict__ bsum_t, int nbS)
{
    const bool isS = (int)blockIdx.x < nbS;
    const int blk = isS ? blockIdx.x : blockIdx.x - nbS;
    const int N = isS ? NS : NT;
    const int* cnt = isS ? cnt_s : cnt_t;
    int* bsum = isS ? bsum_s : bsum_t;
    __shared__ int sdata[256];
    const int t = threadIdx.x;
    const int base = blk * 1024;
    int s = 0;
    for (int i = t; i < 1024; i += 256) {
        int idx = base + i;
        s += (idx < N) ? cnt[idx] : 0;
    }
    sdata[t] = s; __syncthreads();
    for (int off = 128; off > 0; off >>= 1) {
        if (t < off) sdata[t] += sdata[t + off];
        __syncthreads();
    }
    if (t == 0) bsum[blk] = sdata[0];
}

__global__ void sbsum_kernel(int* __restrict__ bsum_s, int* __restrict__ bsum_t,
                             int nbS, int nbT)
{
    if (threadIdx.x != 0) return;
    int* b = blockIdx.x ? bsum_t : bsum_s;
    int nb = blockIdx.x ? nbT : nbS;
    int run = 0;
    for (int i = 0; i < nb; i++) { int v = b[i]; b[i] = run; run += v; }
}

__global__ __launch_bounds__(256) void sblock_kernel(
    const int* __restrict__ cnt_s, const int* __restrict__ cnt_t,
    const int* __restrict__ bsum_s, const int* __restrict__ bsum_t,
    int* __restrict__ rowptr_s, int* __restrict__ rowptr_t, int nbS)
{
    const bool isS = (int)blockIdx.x < nbS;
    const int blk = isS ? blockIdx.x : blockIdx.x - nbS;
    const int N = isS ? NS : NT;
    const int* cnt = isS ? cnt_s : cnt_t;
    const int* bsum = isS ? bsum_s : bsum_t;
    int* rowptr = isS ? rowptr_s : rowptr_t;
    __shared__ int sc[256];
    const int t = threadIdx.x;
    const int base = blk * 1024 + t * 4;
    int v[4]; int s = 0;
#pragma unroll
    for (int j = 0; j < 4; j++) {
        int idx = base + j;
        v[j] = (idx < N) ? cnt[idx] : 0;
        s += v[j];
    }
    sc[t] = s; __syncthreads();
    for (int off = 1; off < 256; off <<= 1) {
        int add = (t >= off) ? sc[t - off] : 0;
        __syncthreads();
        sc[t] += add;
        __syncthreads();
    }
    int excl = sc[t] - s + bsum[blk];
#pragma unroll
    for (int j = 0; j < 4; j++) {
        int idx = base + j;
        if (idx < N) rowptr[idx] = excl;
        if (idx == N - 1) rowptr[N] = excl + v[j];
        excl += v[j];
    }
}

__global__ void binit_kernel(const int* __restrict__ rowptr_t,
                             const int* __restrict__ rowptr_s,
                             int* __restrict__ gcur_t, int* __restrict__ gcur_s)
{
    int t = threadIdx.x;
    if (t < NB_T) gcur_t[t] = rowptr_t[t << SH_T];
    if (t < NB_S) gcur_s[t] = rowptr_s[t << SH_S];
}

__global__ __launch_bounds__(256) void binA_kernel(
    const int* __restrict__ key, const int* __restrict__ val, int E,
    int nbins, int shift, int vbits,
    int* __restrict__ gcur, unsigned* __restrict__ stg)
{
    __shared__ unsigned bins[NB_S * BIN_CAP];
    __shared__ int lcnt[NB_S], gbase[NB_S];
    const int tid = threadIdx.x;
    const int base = blockIdx.x * CHUNK;
    for (int i = tid; i < nbins; i += 256) lcnt[i] = 0;
    __syncthreads();
    const unsigned lowmask = (1u << shift) - 1u;
#pragma unroll
    for (int k = 0; k < CHUNK / 256; k++) {
        int e = base + k * 256 + tid;
        if (e < E) {
            int kk = key[e];
            int b = kk >> shift;
            unsigned pk = (((unsigned)kk & lowmask) << vbits) | (unsigned)val[e];
            int c = atomicAdd(&lcnt[b], 1);
            if (c < BIN_CAP) bins[b * BIN_CAP + c] = pk;
            else { int p = atomicAdd(&gcur[b], 1); stg[p] = pk; }
        }
    }
    __syncthreads();
    if (tid < nbins) gbase[tid] = atomicAdd(&gcur[tid], min(lcnt[tid], BIN_CAP));
    __syncthreads();
    for (int b = 0; b < nbins; b++) {
        int c = min(lcnt[b], BIN_CAP);
        for (int i = tid; i < c; i += 256) stg[gbase[b] + i] = bins[b * BIN_CAP + i];
    }
}

__global__ __launch_bounds__(256) void binB_kernel(
    const unsigned* __restrict__ stg, const int* __restrict__ rowptr,
    int N, int node_per, int vbits, int* __restrict__ colout)
{
    __shared__ int cur[1024];
    const int tid = threadIdx.x;
    const int node0 = blockIdx.x * node_per;
    const int nn = min(node_per, N - node0);
    for (int i = tid; i < nn; i += 256) cur[i] = rowptr[node0 + i];
    const int estart = rowptr[node0];
    const int eend = rowptr[node0 + nn];
    __syncthreads();
    const unsigned vmask = (1u << vbits) - 1u;
    for (int i = estart + tid; i < eend; i += 256) {
        unsigned v = stg[i];
        int kl = (int)(v >> vbits);
        int pos = atomicAdd(&cur[kl], 1);
        colout[pos] = (int)(v & vmask);
    }
}

// ------------------------- per-edge score (fp16 U/V) -----------------------
__global__ __launch_bounds__(256) void edge_score_kernel(
    const _Float16* __restrict__ U, const _Float16* __restrict__ V,
    const int* __restrict__ ls, const int* __restrict__ ld,
    const float* __restrict__ Wd2, const float* __restrict__ bd2,
    float* __restrict__ out, int EL)
{
    const int l32 = threadIdx.x & 31;
    const int e = blockIdx.x * 8 + (threadIdx.x >> 5);
    if (e >= EL) return;
    const int c = l32 * 8;
    half8v u = *(const half8v*)&U[(size_t)ls[e] * 256 + c];
    half8v v = *(const half8v*)&V[(size_t)ld[e] * 256 + c];
    float4 w0 = *(const float4*)&Wd2[c];
    float4 w1 = *(const float4*)&Wd2[c + 4];
    float s = fmaxf((float)u[0] + (float)v[0], 0.f) * w0.x
            + fmaxf((float)u[1] + (float)v[1], 0.f) * w0.y
            + fmaxf((float)u[2] + (float)v[2], 0.f) * w0.z
            + fmaxf((float)u[3] + (float)v[3], 0.f) * w0.w
            + fmaxf((float)u[4] + (float)v[4], 0.f) * w1.x
            + fmaxf((float)u[5] + (float)v[5], 0.f) * w1.y
            + fmaxf((float)u[6] + (float)v[6], 0.f) * w1.z
            + fmaxf((float)u[7] + (float)v[7], 0.f) * w1.w;
#pragma unroll
    for (int m = 16; m >= 1; m >>= 1) s += __shfl_xor(s, m, 64);
    if (l32 == 0) out[e] = s + bd2[0];
}

// ---------------------------------------------------------------------------
extern "C" void kernel_launch(void* const* d_in, const int* in_sizes, int n_in,
                              void* d_out, int out_size, void* d_ws, size_t ws_size,
                              hipStream_t stream)
{
    const float* x_sotu  = (const float*)d_in[0];
    const float* x_taxon = (const float*)d_in[1];
    const int* edge_src  = (const int*)d_in[2];
    const int* edge_dst  = (const int*)d_in[3];
    const int* label_src = (const int*)d_in[4];
    const int* label_dst = (const int*)d_in[5];
    const float* Wl1_st = (const float*)d_in[6];
    const float* bl1_st = (const float*)d_in[7];
    const float* Wr1_st = (const float*)d_in[8];
    const float* Wl1_ts = (const float*)d_in[9];
    const float* bl1_ts = (const float*)d_in[10];
    const float* Wr1_ts = (const float*)d_in[11];
    const float* Wl2_st = (const float*)d_in[12];
    const float* bl2_st = (const float*)d_in[13];
    const float* Wr2_st = (const float*)d_in[14];
    const float* Wl2_ts = (const float*)d_in[15];
    const float* bl2_ts = (const float*)d_in[16];
    const float* Wr2_ts = (const float*)d_in[17];
    const float* Wlin_s = (const float*)d_in[18];
    const float* blin_s = (const float*)d_in[19];
    const float* Wlin_t = (const float*)d_in[20];
    const float* blin_t = (const float*)d_in[21];
    const float* Wd1 = (const float*)d_in[22];
    const float* bd1 = (const float*)d_in[23];
    const float* Wd2 = (const float*)d_in[24];
    const float* bd2 = (const float*)d_in[25];

    // -------- workspace layout --------
    int* wi = (int*)d_ws;
    size_t io = 0;
    int* cnt_s   = wi + io; io += NS;
    int* cnt_t   = wi + io; io += NT;
    int* rowptr_s = wi + io; io += NS + 8;
    int* rowptr_t = wi + io; io += NT + 8;
    int* col_s   = wi + io; io += E_EDGES;
    int* col_t   = wi + io; io += E_EDGES;
    unsigned* stg_s = (unsigned*)(wi + io); io += E_EDGES;
    unsigned* stg_t = (unsigned*)(wi + io); io += E_EDGES;
    int* bsum_s  = wi + io; io += 128;
    int* bsum_t  = wi + io; io += 128;
    int* gcur_t  = wi + io; io += 128;
    int* gcur_s  = wi + io; io += 128;
    io = (io + 63) & ~(size_t)63;

    ushort_t* wb = (ushort_t*)(wi + io);
    size_t bo = 0;
    ushort_t* m_s  = wb + bo; bo += (size_t)NS * H;   // U (fp16) overlays m_s
    ushort_t* h1_s = wb + bo; bo += (size_t)NS * H;
    ushort_t* m_t  = wb + bo; bo += (size_t)NT * H;   // V (fp16) overlays m_t
    ushort_t* h1_t = wb + bo; bo += (size_t)NT * H;
    ushort_t* h2_s = wb + bo; bo += (size_t)NS * H;
    ushort_t* h2_t = wb + bo; bo += (size_t)NT * H;
    ushort_t* xs_b = wb + bo; bo += (size_t)NS * DS;
    ushort_t* xt_b = wb + bo; bo += (size_t)NT * DT;
    ushort_t* Pt   = wb + bo; bo += (size_t)NT * H;
    ushort_t* wb_l1st = wb + bo; bo += H * DS;
    ushort_t* wb_r1st = wb + bo; bo += H * DT;
    ushort_t* wb_l1ts = wb + bo; bo += H * DT;
    ushort_t* wb_r1ts = wb + bo; bo += H * DS;
    ushort_t* wb_l2st = wb + bo; bo += H * H;
    ushort_t* wb_r2st = wb + bo; bo += H * H;
    ushort_t* wb_l2ts = wb + bo; bo += H * H;
    ushort_t* wb_r2ts = wb + bo; bo += H * H;
    ushort_t* wcb_s   = wb + bo; bo += H * H;
    ushort_t* wcb_t   = wb + bo; bo += H * H;
    bo = (bo + 7) & ~(size_t)7;

    float* wf = (float*)(wb + bo);
    size_t fo = 0;
    float* Wc_s = wf + fo; fo += H * H;
    float* Wc_t = wf + fo; fo += H * H;
    float* bu   = wf + fo; fo += 256;
    float* bv   = wf + fo; fo += 256;

    _Float16* U = (_Float16*)m_s;
    _Float16* V = (_Float16*)m_t;

    const dim3 blk(256);
    const dim3 blk512(512);
    auto mgn = [](int M) { return ((M + 127) / 128) * 2; };   // gemm blocks
    auto ggn = [](int N) { return (N + 15) / 16; };           // gather blocks
    const int nbS = (NS + 1023) / 1024;   // 98
    const int nbT = (NT + 1023) / 1024;   // 20
    const int nA = (E_EDGES + CHUNK - 1) / CHUNK;

    // ---- decoder weight folding ----
    fold_kernel<<<513, blk, 0, stream>>>(Wd1, bd1, Wlin_s, blin_s, Wlin_t, blin_t,
                                         Wc_s, Wc_t, bu, bv);

    // ---- edge-degree count (separate dispatch, ILP-4) ----
    hipMemsetAsync(cnt_s, 0, (size_t)(NS + NT) * sizeof(int), stream);
    count_kernel<<<(E_EDGES + 1023) / 1024, blk, 0, stream>>>(
        edge_src, edge_dst, cnt_s, cnt_t, E_EDGES);

    // ---- ILP-4 fp32->bf16 convert (separate dispatch) ----
    {
        CvtJobs jb; int c = 0, total4 = 0;
        auto addj = [&](const float* s, ushort_t* d, int n) {
            jb.src[c] = s; jb.dst[c] = d; jb.n4[c] = n / 4; total4 += n / 4; c++;
        };
        addj(x_sotu, xs_b, NS * DS);
        addj(x_taxon, xt_b, NT * DT);
        addj(Wl1_st, wb_l1st, H * DS);
        addj(Wr1_st, wb_r1st, H * DT);
        addj(Wl1_ts, wb_l1ts, H * DT);
        addj(Wr1_ts, wb_r1ts, H * DS);
        addj(Wl2_st, wb_l2st, H * H);
        addj(Wr2_st, wb_r2st, H * H);
        addj(Wl2_ts, wb_l2ts, H * H);
        addj(Wr2_ts, wb_r2ts, H * H);
        addj(Wc_s, wcb_s, H * H);
        addj(Wc_t, wcb_t, H * H);
        jb.cnt = c;
        const int nchunks = total4 >> 10;  // every n4 is a multiple of 1024
        const int cvb = nchunks < CVT_BLOCKS ? nchunks : CVT_BLOCKS;
        cvt_kernel<<<cvb, blk, 0, stream>>>(jb, nchunks);
    }

    // ---- CSR build: scan -> binned two-pass fill ----
    psum_kernel<<<nbS + nbT, blk, 0, stream>>>(cnt_s, cnt_t, bsum_s, bsum_t, nbS);
    sbsum_kernel<<<2, 64, 0, stream>>>(bsum_s, bsum_t, nbS, nbT);
    sblock_kernel<<<nbS + nbT, blk, 0, stream>>>(cnt_s, cnt_t, bsum_s, bsum_t,
                                                 rowptr_s, rowptr_t, nbS);
    binit_kernel<<<1, blk, 0, stream>>>(rowptr_t, rowptr_s, gcur_t, gcur_s);
    binA_kernel<<<nA, blk, 0, stream>>>(edge_dst, edge_src, E_EDGES,
                                        NB_T, SH_T, VB_T, gcur_t, stg_t);
    binA_kernel<<<nA, blk, 0, stream>>>(edge_src, edge_dst, E_EDGES,
                                        NB_S, SH_S, VB_S, gcur_s, stg_s);
    binB_kernel<<<NB_T, blk, 0, stream>>>(stg_t, rowptr_t, NT, 1 << SH_T, VB_T, col_t);
    binB_kernel<<<NB_S, blk, 0, stream>>>(stg_s, rowptr_s, NS, 1 << SH_S, VB_S, col_s);

    // ---- layer 1 ----
    {   // Pt = xt @ Wl1_ts^T  ||  m_t = gather-mean(xs)
        GemmJob a{xt_b, wb_l1ts, DT, nullptr, nullptr, 0, nullptr, nullptr, Pt, NT, 0};
        GatherJob g{xs_b, rowptr_t, cnt_t, col_t, m_t, NT};
        const int ab = mgn(NT);
        gemm_gather_kernel<<<ab + ggn(NT), blk512, 0, stream>>>(a, ab, g);
    }
    {   // h1_t = relu(m_t@Wl1_st + xt@Wr1_st + b)  ||  m_s = gather-mean(Pt)
        GemmJob a{m_t, wb_l1st, H, xt_b, wb_r1st, DT, nullptr, bl1_st, h1_t, NT, 1};
        GatherJob g{Pt, rowptr_s, cnt_s, col_s, m_s, NS};
        const int ab = mgn(NT);
        gemm_gather_kernel<<<ab + ggn(NS), blk512, 0, stream>>>(a, ab, g);
    }
    {   // h1_s = relu(xs@Wr1_ts + m_s + b)
        GemmJob a{xs_b, wb_r1ts, DS, nullptr, nullptr, 0, m_s, bl1_ts, h1_s, NS, 1};
        mgemm_kernel<<<mgn(NS), blk512, 0, stream>>>(a);
    }

    // ---- layer 2 ----
    {   // Pt = h1_t @ Wl2_ts^T  ||  m_t = gather-mean(h1_s)
        GemmJob a{h1_t, wb_l2ts, H, nullptr, nullptr, 0, nullptr, nullptr, Pt, NT, 0};
        GatherJob g{h1_s, rowptr_t, cnt_t, col_t, m_t, NT};
        const int ab = mgn(NT);
        gemm_gather_kernel<<<ab + ggn(NT), blk512, 0, stream>>>(a, ab, g);
    }
    {   // h2_t = relu(m_t@Wl2_st + h1_t@Wr2_st + b)  ||  m_s = gather-mean(Pt)
        GemmJob a{m_t, wb_l2st, H, h1_t, wb_r2st, H, nullptr, bl2_st, h2_t, NT, 1};
        GatherJob g{Pt, rowptr_s, cnt_s, col_s, m_s, NS};
        const int ab = mgn(NT);
        gemm_gather_kernel<<<ab + ggn(NS), blk512, 0, stream>>>(a, ab, g);
    }
    {   // h2_s = relu(h1_s@Wr2_ts + m_s + b)
        GemmJob a{h1_s, wb_r2ts, H, nullptr, nullptr, 0, m_s, bl2_ts, h2_s, NS, 1};
        mgemm_kernel<<<mgn(NS), blk512, 0, stream>>>(a);
    }

    // ---- decoder: U (NS) || V (NT) node potentials (fp16 out) ----
    {
        GemmJob a{h2_s, wcb_s, H, nullptr, nullptr, 0, nullptr, bu, U, NS, 2};
        GemmJob b{h2_t, wcb_t, H, nullptr, nullptr, 0, nullptr, bv, V, NT, 2};
        const int ab = mgn(NS);
        gemm_gemm_kernel<<<ab + mgn(NT), blk512, 0, stream>>>(a, ab, b);
    }
    edge_score_kernel<<<(EL_EDGES + 7) / 8, blk, 0, stream>>>(
        U, V, label_src, label_dst, Wd2, bd2, (float*)d_out, EL_EDGES);
}

// Round 9
// 794.974 us; speedup vs baseline: 1.1653x; 1.1653x over previous
//
#include <hip/hip_runtime.h>

// ---------------------------------------------------------------------------
// Hetero GraphSAGE (2 layers) + edge decoder.
// R1: CSR-gather aggregation. R5: bf16 MFMA GEMMs. R6: fp16 U/V.
// R8: two-pass LDS-binned CSR fill. R10: XCD-paired swizzle.
// R12: 512-thread mgemm, 32x64 wave tile (proven 74.5us NS-GEMM).
// R13/R14: W-in-LDS GEMM — REGRESSED, reverted. R15: dispatch fusion.
// R16-R19: cvt restructures — flat. R20: cvt/count unfused (both <88us now).
// R21 (this): aggregate-then-project (mean and matmul commute; reference
//   aggregates FIRST). Gather RAW features, fold projection into consumer
//   GEMM as 2nd pass:
//   L1: mxt_s = gmean(xt) [256B rows, 205MB vs 410MB; 5MB table fits XCD-L2];
//       h1_s = relu(xs@Wr1' + mxt_s@Wl1' + b).  Pt-GEMM ELIMINATED.
//   L2: mh_s = gmean(h1_t); h2_s = relu(h1_s@Wr2' + mh_s@Wl2' + b).
//       Pt2-GEMM ELIMINATED.
//   Each layer = [gather||gather] + [NS-GEMM||NT-GEMM]. 2 fewer NT-GEMMs,
//   2 fewer dispatches, no Add stream in NS-GEMMs, no Pt buffer.
// ---------------------------------------------------------------------------

constexpr int NS = 100000, NT = 20000;
constexpr int E_EDGES = 800000, EL_EDGES = 200000;
constexpr int DS = 256, DT = 128, H = 256;

constexpr int NB_T = 79, SH_T = 8, VB_T = 17;
constexpr int NB_S = 98, SH_S = 10, VB_S = 15;
constexpr int BIN_CAP = 96, CHUNK = 2048;
constexpr int CVT_BLOCKS = 2048;

typedef __attribute__((ext_vector_type(8))) short short8;
typedef __attribute__((ext_vector_type(4))) float float4v;
typedef __attribute__((ext_vector_type(8))) _Float16 half8v;
typedef unsigned short ushort_t;

__device__ __forceinline__ float bf2f(unsigned int u) {
    union { unsigned int i; float f; } x; x.i = u << 16; return x.f;
}
__device__ __forceinline__ unsigned short f2bf(float f) {
    union { float f; unsigned int i; } x; x.f = f;
    unsigned int r = x.i + 0x7FFFu + ((x.i >> 16) & 1u);   // RNE
    return (unsigned short)(r >> 16);
}

// --------------------------- MFMA GEMM body (R12, proven) ------------------
// C[M,256] = op( A1@W1^T [+ A2@W2^T] [+ Add] [+ bias] )
// 128x128 block tile, BK=32, LDS stride 40, XCD-paired swizzle, reg prefetch.
// 512 threads / 8 waves; wave (g=wave>>1, h=wave&1) owns rows
// [32g,32g+32) x cols [64h,64h+64): acc[2][4], 32 AGPR/wave.
// flags: 1 = relu, 2 = fp16 output (else bf16)

struct GemmJob {
    const ushort_t* A1; const ushort_t* W1; int K1;
    const ushort_t* A2; const ushort_t* W2; int K2;
    const ushort_t* Add; const float* bias;
    void* C; int M; int flags;
};

struct GatherJob {        // D=256 rows
    const ushort_t* X; const int* rowptr; const int* cnt; const int* col;
    ushort_t* out; int N;
};

struct Gather128Job {     // D=128 rows
    const ushort_t* X; const int* rowptr; const int* cnt; const int* col;
    ushort_t* out; int N;
};

__device__ __forceinline__ void gemm_body(const GemmJob& jb, int bid)
{
    __shared__ ushort_t As[128][40];
    __shared__ ushort_t Bs[128][40];
    const int tid = threadIdx.x;
    const int M = jb.M;

    // ---- XCD-paired swizzle: bid -> (rowblk, colblk) ----
    const int nx = (M + 127) >> 7;          // row-blocks
    const int nx8 = nx & ~7;                // swizzled region (multiple of 8)
    int rowblk, colblk;
    if (bid < nx8 * 2) {
        const int group = bid >> 4;         // 16 blocks per group
        const int xcd = bid & 7;
        const int half = (bid >> 3) & 1;
        rowblk = group * 8 + xcd;
        colblk = half;
    } else {
        const int r = bid - nx8 * 2;
        rowblk = nx8 + (r >> 1);
        colblk = r & 1;
    }
    const int row0 = rowblk * 128, col0 = colblk * 128;

    const int wave = tid >> 6, lane = tid & 63;
    const int wrow = (wave >> 1) * 32;      // 4 row-groups of 32
    const int wcol = (wave & 1) * 64;       // 2 col-groups of 64
    const int m16 = lane & 15, quad = lane >> 4;
    const int sr = tid >> 2;                // staging row 0..127
    const int skc = (tid & 3) * 8;          // k-chunk (ushorts): 0,8,16,24

    float4v acc[2][4];
#pragma unroll
    for (int i = 0; i < 2; i++)
#pragma unroll
        for (int j = 0; j < 4; j++) acc[i][j] = (float4v){0.f, 0.f, 0.f, 0.f};

#pragma unroll 1
    for (int pass = 0; pass < 2; pass++) {
        const ushort_t* A = pass ? jb.A2 : jb.A1;
        const ushort_t* W = pass ? jb.W2 : jb.W1;
        const int K = pass ? jb.K2 : jb.K1;
        if (!A) break;
        const int gra = row0 + sr;
        const bool oka = gra < M;
        const ushort_t* Ap = A + (size_t)gra * K + skc;
        const ushort_t* Wp = W + (size_t)(col0 + sr) * K + skc;

        // preload tile 0
        uint4 a0 = make_uint4(0, 0, 0, 0);
        if (oka) a0 = *(const uint4*)Ap;
        uint4 b0 = *(const uint4*)Wp;

        for (int k0 = 0; k0 < K; k0 += 32) {
            __syncthreads();                 // prev iter done reading LDS
            *(uint4*)&As[sr][skc] = a0;
            *(uint4*)&Bs[sr][skc] = b0;
            __syncthreads();                 // LDS ready
            if (k0 + 32 < K) {               // prefetch tile k+1
                a0 = make_uint4(0, 0, 0, 0);
                if (oka) a0 = *(const uint4*)(Ap + k0 + 32);
                b0 = *(const uint4*)(Wp + k0 + 32);
            }
            short8 af[2], bf[4];
#pragma unroll
            for (int i = 0; i < 2; i++)
                af[i] = *(const short8*)&As[wrow + i * 16 + m16][quad * 8];
#pragma unroll
            for (int j = 0; j < 4; j++)
                bf[j] = *(const short8*)&Bs[wcol + j * 16 + m16][quad * 8];
#pragma unroll
            for (int i = 0; i < 2; i++)
#pragma unroll
                for (int j = 0; j < 4; j++)
                    acc[i][j] = __builtin_amdgcn_mfma_f32_16x16x32_bf16(
                        af[i], bf[j], acc[i][j], 0, 0, 0);
        }
    }

    const bool relu = jb.flags & 1, f16out = jb.flags & 2;
#pragma unroll
    for (int i = 0; i < 2; i++) {
        const int rbase = row0 + wrow + i * 16 + quad * 4;
#pragma unroll
        for (int r = 0; r < 4; r++) {
            const int row = rbase + r;
            if (row >= M) continue;
#pragma unroll
            for (int j = 0; j < 4; j++) {
                const int col = col0 + wcol + j * 16 + m16;
                float v = acc[i][j][r];
                if (jb.Add) v += bf2f((unsigned int)jb.Add[(size_t)row * 256 + col]);
                if (jb.bias) v += jb.bias[col];
                if (relu) v = fmaxf(v, 0.f);
                if (f16out) ((_Float16*)jb.C)[(size_t)row * 256 + col] = (_Float16)v;
                else ((ushort_t*)jb.C)[(size_t)row * 256 + col] = f2bf(v);
            }
        }
    }
}

// ---------------- gather mean bodies (bf16 rows, fp32 accum) ---------------
// D=256: 512 threads, 16 nodes/block, 32 lanes per node (8 cols each).
__device__ __forceinline__ void gather_body(const GatherJob& g, int gb)
{
    const int node = gb * 16 + (threadIdx.x >> 5);
    const int c = (threadIdx.x & 31) * 8;
    if (node >= g.N) return;
    const int beg = g.rowptr[node];
    const int deg = g.cnt[node];
    const int end = beg + deg;
    const ushort_t* __restrict__ X = g.X;
    const int* __restrict__ col = g.col;
    float a[8] = {0, 0, 0, 0, 0, 0, 0, 0};
    float b[8] = {0, 0, 0, 0, 0, 0, 0, 0};
    int i = beg;
    for (; i + 1 < end; i += 2) {
        uint4 v = *(const uint4*)&X[(size_t)col[i] * 256 + c];
        uint4 w = *(const uint4*)&X[(size_t)col[i + 1] * 256 + c];
        a[0] += bf2f(v.x & 0xffff); a[1] += bf2f(v.x >> 16);
        a[2] += bf2f(v.y & 0xffff); a[3] += bf2f(v.y >> 16);
        a[4] += bf2f(v.z & 0xffff); a[5] += bf2f(v.z >> 16);
        a[6] += bf2f(v.w & 0xffff); a[7] += bf2f(v.w >> 16);
        b[0] += bf2f(w.x & 0xffff); b[1] += bf2f(w.x >> 16);
        b[2] += bf2f(w.y & 0xffff); b[3] += bf2f(w.y >> 16);
        b[4] += bf2f(w.z & 0xffff); b[5] += bf2f(w.z >> 16);
        b[6] += bf2f(w.w & 0xffff); b[7] += bf2f(w.w >> 16);
    }
    if (i < end) {
        uint4 v = *(const uint4*)&X[(size_t)col[i] * 256 + c];
        a[0] += bf2f(v.x & 0xffff); a[1] += bf2f(v.x >> 16);
        a[2] += bf2f(v.y & 0xffff); a[3] += bf2f(v.y >> 16);
        a[4] += bf2f(v.z & 0xffff); a[5] += bf2f(v.z >> 16);
        a[6] += bf2f(v.w & 0xffff); a[7] += bf2f(v.w >> 16);
    }
    float inv = 1.f / fmaxf((float)deg, 1.f);
    uint4 o;
    o.x = (unsigned int)f2bf((a[0] + b[0]) * inv) | ((unsigned int)f2bf((a[1] + b[1]) * inv) << 16);
    o.y = (unsigned int)f2bf((a[2] + b[2]) * inv) | ((unsigned int)f2bf((a[3] + b[3]) * inv) << 16);
    o.z = (unsigned int)f2bf((a[4] + b[4]) * inv) | ((unsigned int)f2bf((a[5] + b[5]) * inv) << 16);
    o.w = (unsigned int)f2bf((a[6] + b[6]) * inv) | ((unsigned int)f2bf((a[7] + b[7]) * inv) << 16);
    *(uint4*)&g.out[(size_t)node * 256 + c] = o;
}

// D=128: 512 threads, 32 nodes/block, 16 lanes per node (8 cols each).
__device__ __forceinline__ void gather128_body(const Gather128Job& g, int gb)
{
    const int node = gb * 32 + (threadIdx.x >> 4);
    const int c = (threadIdx.x & 15) * 8;
    if (node >= g.N) return;
    const int beg = g.rowptr[node];
    const int deg = g.cnt[node];
    const int end = beg + deg;
    const ushort_t* __restrict__ X = g.X;
    const int* __restrict__ col = g.col;
    float a[8] = {0, 0, 0, 0, 0, 0, 0, 0};
    float b[8] = {0, 0, 0, 0, 0, 0, 0, 0};
    int i = beg;
    for (; i + 1 < end; i += 2) {
        uint4 v = *(const uint4*)&X[(size_t)col[i] * 128 + c];
        uint4 w = *(const uint4*)&X[(size_t)col[i + 1] * 128 + c];
        a[0] += bf2f(v.x & 0xffff); a[1] += bf2f(v.x >> 16);
        a[2] += bf2f(v.y & 0xffff); a[3] += bf2f(v.y >> 16);
        a[4] += bf2f(v.z & 0xffff); a[5] += bf2f(v.z >> 16);
        a[6] += bf2f(v.w & 0xffff); a[7] += bf2f(v.w >> 16);
        b[0] += bf2f(w.x & 0xffff); b[1] += bf2f(w.x >> 16);
        b[2] += bf2f(w.y & 0xffff); b[3] += bf2f(w.y >> 16);
        b[4] += bf2f(w.z & 0xffff); b[5] += bf2f(w.z >> 16);
        b[6] += bf2f(w.w & 0xffff); b[7] += bf2f(w.w >> 16);
    }
    if (i < end) {
        uint4 v = *(const uint4*)&X[(size_t)col[i] * 128 + c];
        a[0] += bf2f(v.x & 0xffff); a[1] += bf2f(v.x >> 16);
        a[2] += bf2f(v.y & 0xffff); a[3] += bf2f(v.y >> 16);
        a[4] += bf2f(v.z & 0xffff); a[5] += bf2f(v.z >> 16);
        a[6] += bf2f(v.w & 0xffff); a[7] += bf2f(v.w >> 16);
    }
    float inv = 1.f / fmaxf((float)deg, 1.f);
    uint4 o;
    o.x = (unsigned int)f2bf((a[0] + b[0]) * inv) | ((unsigned int)f2bf((a[1] + b[1]) * inv) << 16);
    o.y = (unsigned int)f2bf((a[2] + b[2]) * inv) | ((unsigned int)f2bf((a[3] + b[3]) * inv) << 16);
    o.z = (unsigned int)f2bf((a[4] + b[4]) * inv) | ((unsigned int)f2bf((a[5] + b[5]) * inv) << 16);
    o.w = (unsigned int)f2bf((a[6] + b[6]) * inv) | ((unsigned int)f2bf((a[7] + b[7]) * inv) << 16);
    *(uint4*)&g.out[(size_t)node * 128 + c] = o;
}

// --------------------------- fused launch shells ---------------------------
__global__ __launch_bounds__(512) void gemm_gemm_kernel(GemmJob a, int ablocks,
                                                        GemmJob b)
{
    const int bid = blockIdx.x;
    if (bid < ablocks) gemm_body(a, bid);
    else gemm_body(b, bid - ablocks);
}

__global__ __launch_bounds__(512) void gather_g128_kernel(GatherJob a, int ablocks,
                                                          Gather128Job b)
{
    const int bid = blockIdx.x;
    if (bid < ablocks) gather_body(a, bid);
    else gather128_body(b, bid - ablocks);
}

__global__ __launch_bounds__(512) void gather_gather_kernel(GatherJob a, int ablocks,
                                                            GatherJob b)
{
    const int bid = blockIdx.x;
    if (bid < ablocks) gather_body(a, bid);
    else gather_body(b, bid - ablocks);
}

// ----------------------- ILP-4 fp32 -> bf16 convert ------------------------
// Every job's float4-count is a multiple of 1024, so a 1024-float4 chunk
// never spans a job boundary: one uniform job-search per chunk, then each
// thread issues 4 independent coalesced loads (t, t+256, t+512, t+768).
struct CvtJobs {
    const float* src[14];
    ushort_t* dst[14];
    int n4[14];
    int cnt;
};

__global__ __launch_bounds__(256) void cvt_kernel(CvtJobs jb, int nchunks)
{
    const int t = threadIdx.x;
#pragma unroll 1
    for (int ch = blockIdx.x; ch < nchunks; ch += gridDim.x) {
        int idx = ch << 10;                // first float4 of this chunk
        int k = 0;
        while (idx >= jb.n4[k]) { idx -= jb.n4[k]; ++k; }   // uniform search
        const float4* __restrict__ s = (const float4*)jb.src[k];
        ushort_t* __restrict__ d = jb.dst[k];
        const int base = idx + t;
        // 4 independent loads in flight before any use
        float4 v0 = s[base];
        float4 v1 = s[base + 256];
        float4 v2 = s[base + 512];
        float4 v3 = s[base + 768];
        uint2 o0, o1, o2, o3;
        o0.x = (unsigned int)f2bf(v0.x) | ((unsigned int)f2bf(v0.y) << 16);
        o0.y = (unsigned int)f2bf(v0.z) | ((unsigned int)f2bf(v0.w) << 16);
        o1.x = (unsigned int)f2bf(v1.x) | ((unsigned int)f2bf(v1.y) << 16);
        o1.y = (unsigned int)f2bf(v1.z) | ((unsigned int)f2bf(v1.w) << 16);
        o2.x = (unsigned int)f2bf(v2.x) | ((unsigned int)f2bf(v2.y) << 16);
        o2.y = (unsigned int)f2bf(v2.z) | ((unsigned int)f2bf(v2.w) << 16);
        o3.x = (unsigned int)f2bf(v3.x) | ((unsigned int)f2bf(v3.y) << 16);
        o3.y = (unsigned int)f2bf(v3.z) | ((unsigned int)f2bf(v3.w) << 16);
        *(uint2*)(d + (size_t)base * 4) = o0;
        *(uint2*)(d + (size_t)(base + 256) * 4) = o1;
        *(uint2*)(d + (size_t)(base + 512) * 4) = o2;
        *(uint2*)(d + (size_t)(base + 768) * 4) = o3;
    }
}

// ----------------------- edge-degree count (ILP-4) -------------------------
__global__ __launch_bounds__(256) void count_kernel(
    const int* __restrict__ src, const int* __restrict__ dst,
    int* __restrict__ cnt_s, int* __restrict__ cnt_t, int E)
{
    const int base = blockIdx.x * 1024 + threadIdx.x;
    const int e0 = base, e1 = base + 256, e2 = base + 512, e3 = base + 768;
    int s0 = 0, s1 = 0, s2 = 0, s3 = 0;
    int d0 = 0, d1 = 0, d2 = 0, d3 = 0;
    if (e0 < E) { s0 = src[e0]; d0 = dst[e0]; }
    if (e1 < E) { s1 = src[e1]; d1 = dst[e1]; }
    if (e2 < E) { s2 = src[e2]; d2 = dst[e2]; }
    if (e3 < E) { s3 = src[e3]; d3 = dst[e3]; }
    if (e0 < E) { atomicAdd(&cnt_s[s0], 1); atomicAdd(&cnt_t[d0], 1); }
    if (e1 < E) { atomicAdd(&cnt_s[s1], 1); atomicAdd(&cnt_t[d1], 1); }
    if (e2 < E) { atomicAdd(&cnt_s[s2], 1); atomicAdd(&cnt_t[d2], 1); }
    if (e3 < E) { atomicAdd(&cnt_s[s3], 1); atomicAdd(&cnt_t[d3], 1); }
}

// -------------- decoder weight folding (one fused kernel) ------------------
__global__ __launch_bounds__(256) void fold_kernel(
    const float* __restrict__ Wd1, const float* __restrict__ bd1,
    const float* __restrict__ Wlin_s, const float* __restrict__ blin_s,
    const float* __restrict__ Wlin_t, const float* __restrict__ blin_t,
    float* __restrict__ Wc_s, float* __restrict__ Wc_t,
    float* __restrict__ bu, float* __restrict__ bv)
{
    const int b = blockIdx.x, t = threadIdx.x;
    if (b < 256) {
        float s = 0.f;
        for (int k = 0; k < 256; k++) s += Wd1[b * 512 + k] * Wlin_s[k * 256 + t];
        Wc_s[b * 256 + t] = s;
    } else if (b < 512) {
        const int h = b - 256;
        float s = 0.f;
        for (int k = 0; k < 256; k++) s += Wd1[h * 512 + 256 + k] * Wlin_t[k * 256 + t];
        Wc_t[h * 256 + t] = s;
    } else {
        float su = 0.f, sv = 0.f;
        for (int k = 0; k < 256; k++) {
            su += Wd1[t * 512 + k] * blin_s[k];
            sv += Wd1[t * 512 + 256 + k] * blin_t[k];
        }
        bu[t] = bd1[t] + su;
        bv[t] = sv;
    }
}

// --------------------------- CSR build -------------------------------------
__global__ __launch_bounds__(256) void psum_kernel(
    const int* __restrict__ cnt_s, const int* __restrict__ cnt_t,
    int* __restrict__ bsum_s, int* __restrict__ bsum_t, int nbS)
{
    const bool isS = (int)blockIdx.x < nbS;
    const int blk = isS ? blockIdx.x : blockIdx.x - nbS;
    const int N = isS ? NS : NT;
    const int* cnt = isS ? cnt_s : cnt_t;
    int* bsum = isS ? bsum_s : bsum_t;
    __shared__ int sdata[256];
    const int t = threadIdx.x;
    const int base = blk * 1024;
    int s = 0;
    for (int i = t; i < 1024; i += 256) {
        int idx = base + i;
        s += (idx < N) ? cnt[idx] : 0;
    }
    sdata[t] = s; __syncthreads();
    for (int off = 128; off > 0; off >>= 1) {
        if (t < off) sdata[t] += sdata[t + off];
        __syncthreads();
    }
    if (t == 0) bsum[blk] = sdata[0];
}

__global__ void sbsum_kernel(int* __restrict__ bsum_s, int* __restrict__ bsum_t,
                             int nbS, int nbT)
{
    if (threadIdx.x != 0) return;
    int* b = blockIdx.x ? bsum_t : bsum_s;
    int nb = blockIdx.x ? nbT : nbS;
    int run = 0;
    for (int i = 0; i < nb; i++) { int v = b[i]; b[i] = run; run += v; }
}

__global__ __launch_bounds__(256) void sblock_kernel(
    const int* __restrict__ cnt_s, const int* __restrict__ cnt_t,
    const int* __restrict__ bsum_s, const int* __restrict__ bsum_t,
    int* __restrict__ rowptr_s, int* __restrict__ rowptr_t, int nbS)
{
    const bool isS = (int)blockIdx.x < nbS;
    const int blk = isS ? blockIdx.x : blockIdx.x - nbS;
    const int N = isS ? NS : NT;
    const int* cnt = isS ? cnt_s : cnt_t;
    const int* bsum = isS ? bsum_s : bsum_t;
    int* rowptr = isS ? rowptr_s : rowptr_t;
    __shared__ int sc[256];
    const int t = threadIdx.x;
    const int base = blk * 1024 + t * 4;
    int v[4]; int s = 0;
#pragma unroll
    for (int j = 0; j < 4; j++) {
        int idx = base + j;
        v[j] = (idx < N) ? cnt[idx] : 0;
        s += v[j];
    }
    sc[t] = s; __syncthreads();
    for (int off = 1; off < 256; off <<= 1) {
        int add = (t >= off) ? sc[t - off] : 0;
        __syncthreads();
        sc[t] += add;
        __syncthreads();
    }
    int excl = sc[t] - s + bsum[blk];
#pragma unroll
    for (int j = 0; j < 4; j++) {
        int idx = base + j;
        if (idx < N) rowptr[idx] = excl;
        if (idx == N - 1) rowptr[N] = excl + v[j];
        excl += v[j];
    }
}

__global__ void binit_kernel(const int* __restrict__ rowptr_t,
                             const int* __restrict__ rowptr_s,
                             int* __restrict__ gcur_t, int* __restrict__ gcur_s)
{
    int t = threadIdx.x;
    if (t < NB_T) gcur_t[t] = rowptr_t[t << SH_T];
    if (t < NB_S) gcur_s[t] = rowptr_s[t << SH_S];
}

__global__ __launch_bounds__(256) void binA_kernel(
    const int* __restrict__ key, const int* __restrict__ val, int E,
    int nbins, int shift, int vbits,
    int* __restrict__ gcur, unsigned* __restrict__ stg)
{
    __shared__ unsigned bins[NB_S * BIN_CAP];
    __shared__ int lcnt[NB_S], gbase[NB_S];
    const int tid = threadIdx.x;
    const int base = blockIdx.x * CHUNK;
    for (int i = tid; i < nbins; i += 256) lcnt[i] = 0;
    __syncthreads();
    const unsigned lowmask = (1u << shift) - 1u;
#pragma unroll
    for (int k = 0; k < CHUNK / 256; k++) {
        int e = base + k * 256 + tid;
        if (e < E) {
            int kk = key[e];
            int b = kk >> shift;
            unsigned pk = (((unsigned)kk & lowmask) << vbits) | (unsigned)val[e];
            int c = atomicAdd(&lcnt[b], 1);
            if (c < BIN_CAP) bins[b * BIN_CAP + c] = pk;
            else { int p = atomicAdd(&gcur[b], 1); stg[p] = pk; }
        }
    }
    __syncthreads();
    if (tid < nbins) gbase[tid] = atomicAdd(&gcur[tid], min(lcnt[tid], BIN_CAP));
    __syncthreads();
    for (int b = 0; b < nbins; b++) {
        int c = min(lcnt[b], BIN_CAP);
        for (int i = tid; i < c; i += 256) stg[gbase[b] + i] = bins[b * BIN_CAP + i];
    }
}

__global__ __launch_bounds__(256) void binB_kernel(
    const unsigned* __restrict__ stg, const int* __restrict__ rowptr,
    int N, int node_per, int vbits, int* __restrict__ colout)
{
    __shared__ int cur[1024];
    const int tid = threadIdx.x;
    const int node0 = blockIdx.x * node_per;
    const int nn = min(node_per, N - node0);
    for (int i = tid; i < nn; i += 256) cur[i] = rowptr[node0 + i];
    const int estart = rowptr[node0];
    const int eend = rowptr[node0 + nn];
    __syncthreads();
    const unsigned vmask = (1u << vbits) - 1u;
    for (int i = estart + tid; i < eend; i += 256) {
        unsigned v = stg[i];
        int kl = (int)(v >> vbits);
        int pos = atomicAdd(&cur[kl], 1);
        colout[pos] = (int)(v & vmask);
    }
}

// ------------------------- per-edge score (fp16 U/V) -----------------------
__global__ __launch_bounds__(256) void edge_score_kernel(
    const _Float16* __restrict__ U, const _Float16* __restrict__ V,
    const int* __restrict__ ls, const int* __restrict__ ld,
    const float* __restrict__ Wd2, const float* __restrict__ bd2,
    float* __restrict__ out, int EL)
{
    const int l32 = threadIdx.x & 31;
    const int e = blockIdx.x * 8 + (threadIdx.x >> 5);
    if (e >= EL) return;
    const int c = l32 * 8;
    half8v u = *(const half8v*)&U[(size_t)ls[e] * 256 + c];
    half8v v = *(const half8v*)&V[(size_t)ld[e] * 256 + c];
    float4 w0 = *(const float4*)&Wd2[c];
    float4 w1 = *(const float4*)&Wd2[c + 4];
    float s = fmaxf((float)u[0] + (float)v[0], 0.f) * w0.x
            + fmaxf((float)u[1] + (float)v[1], 0.f) * w0.y
            + fmaxf((float)u[2] + (float)v[2], 0.f) * w0.z
            + fmaxf((float)u[3] + (float)v[3], 0.f) * w0.w
            + fmaxf((float)u[4] + (float)v[4], 0.f) * w1.x
            + fmaxf((float)u[5] + (float)v[5], 0.f) * w1.y
            + fmaxf((float)u[6] + (float)v[6], 0.f) * w1.z
            + fmaxf((float)u[7] + (float)v[7], 0.f) * w1.w;
#pragma unroll
    for (int m = 16; m >= 1; m >>= 1) s += __shfl_xor(s, m, 64);
    if (l32 == 0) out[e] = s + bd2[0];
}

// ---------------------------------------------------------------------------
extern "C" void kernel_launch(void* const* d_in, const int* in_sizes, int n_in,
                              void* d_out, int out_size, void* d_ws, size_t ws_size,
                              hipStream_t stream)
{
    const float* x_sotu  = (const float*)d_in[0];
    const float* x_taxon = (const float*)d_in[1];
    const int* edge_src  = (const int*)d_in[2];
    const int* edge_dst  = (const int*)d_in[3];
    const int* label_src = (const int*)d_in[4];
    const int* label_dst = (const int*)d_in[5];
    const float* Wl1_st = (const float*)d_in[6];
    const float* bl1_st = (const float*)d_in[7];
    const float* Wr1_st = (const float*)d_in[8];
    const float* Wl1_ts = (const float*)d_in[9];
    const float* bl1_ts = (const float*)d_in[10];
    const float* Wr1_ts = (const float*)d_in[11];
    const float* Wl2_st = (const float*)d_in[12];
    const float* bl2_st = (const float*)d_in[13];
    const float* Wr2_st = (const float*)d_in[14];
    const float* Wl2_ts = (const float*)d_in[15];
    const float* bl2_ts = (const float*)d_in[16];
    const float* Wr2_ts = (const float*)d_in[17];
    const float* Wlin_s = (const float*)d_in[18];
    const float* blin_s = (const float*)d_in[19];
    const float* Wlin_t = (const float*)d_in[20];
    const float* blin_t = (const float*)d_in[21];
    const float* Wd1 = (const float*)d_in[22];
    const float* bd1 = (const float*)d_in[23];
    const float* Wd2 = (const float*)d_in[24];
    const float* bd2 = (const float*)d_in[25];

    // -------- workspace layout --------
    int* wi = (int*)d_ws;
    size_t io = 0;
    int* cnt_s   = wi + io; io += NS;
    int* cnt_t   = wi + io; io += NT;
    int* rowptr_s = wi + io; io += NS + 8;
    int* rowptr_t = wi + io; io += NT + 8;
    int* col_s   = wi + io; io += E_EDGES;
    int* col_t   = wi + io; io += E_EDGES;
    unsigned* stg_s = (unsigned*)(wi + io); io += E_EDGES;
    unsigned* stg_t = (unsigned*)(wi + io); io += E_EDGES;
    int* bsum_s  = wi + io; io += 128;
    int* bsum_t  = wi + io; io += 128;
    int* gcur_t  = wi + io; io += 128;
    int* gcur_s  = wi + io; io += 128;
    io = (io + 63) & ~(size_t)63;

    ushort_t* wb = (ushort_t*)(wi + io);
    size_t bo = 0;
    ushort_t* m_s  = wb + bo; bo += (size_t)NS * H;   // mxt/mh gather out; U overlays
    ushort_t* h1_s = wb + bo; bo += (size_t)NS * H;
    ushort_t* m_t  = wb + bo; bo += (size_t)NT * H;   // V (fp16) overlays m_t
    ushort_t* h1_t = wb + bo; bo += (size_t)NT * H;
    ushort_t* h2_s = wb + bo; bo += (size_t)NS * H;
    ushort_t* h2_t = wb + bo; bo += (size_t)NT * H;
    ushort_t* xs_b = wb + bo; bo += (size_t)NS * DS;
    ushort_t* xt_b = wb + bo; bo += (size_t)NT * DT;
    ushort_t* wb_l1st = wb + bo; bo += H * DS;
    ushort_t* wb_r1st = wb + bo; bo += H * DT;
    ushort_t* wb_l1ts = wb + bo; bo += H * DT;
    ushort_t* wb_r1ts = wb + bo; bo += H * DS;
    ushort_t* wb_l2st = wb + bo; bo += H * H;
    ushort_t* wb_r2st = wb + bo; bo += H * H;
    ushort_t* wb_l2ts = wb + bo; bo += H * H;
    ushort_t* wb_r2ts = wb + bo; bo += H * H;
    ushort_t* wcb_s   = wb + bo; bo += H * H;
    ushort_t* wcb_t   = wb + bo; bo += H * H;
    bo = (bo + 7) & ~(size_t)7;

    float* wf = (float*)(wb + bo);
    size_t fo = 0;
    float* Wc_s = wf + fo; fo += H * H;
    float* Wc_t = wf + fo; fo += H * H;
    float* bu   = wf + fo; fo += 256;
    float* bv   = wf + fo; fo += 256;

    _Float16* U = (_Float16*)m_s;
    _Float16* V = (_Float16*)m_t;

    const dim3 blk(256);
    const dim3 blk512(512);
    auto mgn = [](int M) { return ((M + 127) / 128) * 2; };   // gemm blocks
    auto g256n = [](int N) { return (N + 15) / 16; };         // D=256 gather blocks
    auto g128n = [](int N) { return (N + 31) / 32; };         // D=128 gather blocks
    const int nbS = (NS + 1023) / 1024;   // 98
    const int nbT = (NT + 1023) / 1024;   // 20
    const int nA = (E_EDGES + CHUNK - 1) / CHUNK;

    // ---- decoder weight folding ----
    fold_kernel<<<513, blk, 0, stream>>>(Wd1, bd1, Wlin_s, blin_s, Wlin_t, blin_t,
                                         Wc_s, Wc_t, bu, bv);

    // ---- edge-degree count (ILP-4) ----
    hipMemsetAsync(cnt_s, 0, (size_t)(NS + NT) * sizeof(int), stream);
    count_kernel<<<(E_EDGES + 1023) / 1024, blk, 0, stream>>>(
        edge_src, edge_dst, cnt_s, cnt_t, E_EDGES);

    // ---- ILP-4 fp32->bf16 convert ----
    {
        CvtJobs jb; int c = 0, total4 = 0;
        auto addj = [&](const float* s, ushort_t* d, int n) {
            jb.src[c] = s; jb.dst[c] = d; jb.n4[c] = n / 4; total4 += n / 4; c++;
        };
        addj(x_sotu, xs_b, NS * DS);
        addj(x_taxon, xt_b, NT * DT);
        addj(Wl1_st, wb_l1st, H * DS);
        addj(Wr1_st, wb_r1st, H * DT);
        addj(Wl1_ts, wb_l1ts, H * DT);
        addj(Wr1_ts, wb_r1ts, H * DS);
        addj(Wl2_st, wb_l2st, H * H);
        addj(Wr2_st, wb_r2st, H * H);
        addj(Wl2_ts, wb_l2ts, H * H);
        addj(Wr2_ts, wb_r2ts, H * H);
        addj(Wc_s, wcb_s, H * H);
        addj(Wc_t, wcb_t, H * H);
        jb.cnt = c;
        const int nchunks = total4 >> 10;  // every n4 is a multiple of 1024
        const int cvb = nchunks < CVT_BLOCKS ? nchunks : CVT_BLOCKS;
        cvt_kernel<<<cvb, blk, 0, stream>>>(jb, nchunks);
    }

    // ---- CSR build: scan -> binned two-pass fill ----
    psum_kernel<<<nbS + nbT, blk, 0, stream>>>(cnt_s, cnt_t, bsum_s, bsum_t, nbS);
    sbsum_kernel<<<2, 64, 0, stream>>>(bsum_s, bsum_t, nbS, nbT);
    sblock_kernel<<<nbS + nbT, blk, 0, stream>>>(cnt_s, cnt_t, bsum_s, bsum_t,
                                                 rowptr_s, rowptr_t, nbS);
    binit_kernel<<<1, blk, 0, stream>>>(rowptr_t, rowptr_s, gcur_t, gcur_s);
    binA_kernel<<<nA, blk, 0, stream>>>(edge_dst, edge_src, E_EDGES,
                                        NB_T, SH_T, VB_T, gcur_t, stg_t);
    binA_kernel<<<nA, blk, 0, stream>>>(edge_src, edge_dst, E_EDGES,
                                        NB_S, SH_S, VB_S, gcur_s, stg_s);
    binB_kernel<<<NB_T, blk, 0, stream>>>(stg_t, rowptr_t, NT, 1 << SH_T, VB_T, col_t);
    binB_kernel<<<NB_S, blk, 0, stream>>>(stg_s, rowptr_s, NS, 1 << SH_S, VB_S, col_s);

    // ---- layer 1: aggregate-then-project ----
    {   // m_t = gmean(xs) [D=256]  ||  mxt_s = gmean(xt) [D=128, in m_s slot]
        GatherJob a{xs_b, rowptr_t, cnt_t, col_t, m_t, NT};
        Gather128Job b{xt_b, rowptr_s, cnt_s, col_s, m_s, NS};
        const int ab = g256n(NT);
        gather_g128_kernel<<<ab + g128n(NS), blk512, 0, stream>>>(a, ab, b);
    }
    {   // h1_s = relu(xs@Wr1_ts' + mxt_s@Wl1_ts' + b)  ||  h1_t = relu(...)
        GemmJob a{xs_b, wb_r1ts, DS, m_s, wb_l1ts, DT, nullptr, bl1_ts, h1_s, NS, 1};
        GemmJob b{m_t, wb_l1st, H, xt_b, wb_r1st, DT, nullptr, bl1_st, h1_t, NT, 1};
        const int ab = mgn(NS);
        gemm_gemm_kernel<<<ab + mgn(NT), blk512, 0, stream>>>(a, ab, b);
    }

    // ---- layer 2: aggregate-then-project ----
    {   // m_t = gmean(h1_s) [D=256]  ||  mh_s = gmean(h1_t) [D=256, m_s slot]
        GatherJob a{h1_s, rowptr_t, cnt_t, col_t, m_t, NT};
        GatherJob b{h1_t, rowptr_s, cnt_s, col_s, m_s, NS};
        const int ab = g256n(NT);
        gather_gather_kernel<<<ab + g256n(NS), blk512, 0, stream>>>(a, ab, b);
    }
    {   // h2_s = relu(h1_s@Wr2_ts' + mh_s@Wl2_ts' + b)  ||  h2_t = relu(...)
        GemmJob a{h1_s, wb_r2ts, H, m_s, wb_l2ts, H, nullptr, bl2_ts, h2_s, NS, 1};
        GemmJob b{m_t, wb_l2st, H, h1_t, wb_r2st, H, nullptr, bl2_st, h2_t, NT, 1};
        const int ab = mgn(NS);
        gemm_gemm_kernel<<<ab + mgn(NT), blk512, 0, stream>>>(a, ab, b);
    }

    // ---- decoder: U (NS) || V (NT) node potentials (fp16 out) ----
    {
        GemmJob a{h2_s, wcb_s, H, nullptr, nullptr, 0, nullptr, bu, U, NS, 2};
        GemmJob b{h2_t, wcb_t, H, nullptr, nullptr, 0, nullptr, bv, V, NT, 2};
        const int ab = mgn(NS);
        gemm_gemm_kernel<<<ab + mgn(NT), blk512, 0, stream>>>(a, ab, b);
    }
    edge_score_kernel<<<(EL_EDGES + 7) / 8, blk, 0, stream>>>(
        U, V, label_src, label_dst, Wd2, bd2, (float*)d_out, EL_EDGES);
}

// Round 10
// 782.256 us; speedup vs baseline: 1.1842x; 1.0163x over previous
//
#include <hip/hip_runtime.h>

// ---------------------------------------------------------------------------
// Hetero GraphSAGE (2 layers) + edge decoder.
// R1: CSR-gather aggregation. R5: bf16 MFMA GEMMs. R6: fp16 U/V.
// R8: two-pass LDS-binned CSR fill. R10: XCD-paired swizzle.
// R12: 512-thread mgemm, 32x64 wave tile. R13/R14: W-in-LDS — reverted.
// R15: dispatch fusion. R16-R20: cvt/count isolated (<40us each).
// R21: aggregate-then-project — 926 -> 795us. Top: L2 gather_gather 106us,
//   3x gemm_gemm ~85-90us each (latency-bound, occupancy 33%).
// R22 (this):
//   (a) GEMM re-tile: 256 threads / 4 waves, 64x128 block tile (same 32x64
//       wave tile + acc[2][4] + stride-40 LDS + swizzle). 2x wave-limit
//       blocks/CU (8 vs 4), 2x finer grid (3126 blocks @NS) -> TLP hides
//       the barrier-separated K-chain latency. Occupancy 33 -> 60%+.
//   (b) Gather ILP-4: 4 col-idx + 4 row loads in flight per iter.
// ---------------------------------------------------------------------------

constexpr int NS = 100000, NT = 20000;
constexpr int E_EDGES = 800000, EL_EDGES = 200000;
constexpr int DS = 256, DT = 128, H = 256;

constexpr int NB_T = 79, SH_T = 8, VB_T = 17;
constexpr int NB_S = 98, SH_S = 10, VB_S = 15;
constexpr int BIN_CAP = 96, CHUNK = 2048;
constexpr int CVT_BLOCKS = 2048;

typedef __attribute__((ext_vector_type(8))) short short8;
typedef __attribute__((ext_vector_type(4))) float float4v;
typedef __attribute__((ext_vector_type(8))) _Float16 half8v;
typedef unsigned short ushort_t;

__device__ __forceinline__ float bf2f(unsigned int u) {
    union { unsigned int i; float f; } x; x.i = u << 16; return x.f;
}
__device__ __forceinline__ unsigned short f2bf(float f) {
    union { float f; unsigned int i; } x; x.f = f;
    unsigned int r = x.i + 0x7FFFu + ((x.i >> 16) & 1u);   // RNE
    return (unsigned short)(r >> 16);
}

// --------------------------- MFMA GEMM body (R22) --------------------------
// C[M,256] = op( A1@W1^T [+ A2@W2^T] [+ Add] [+ bias] )
// 64x128 block tile, BK=32, LDS stride 40, XCD-paired swizzle, reg prefetch.
// 256 threads / 4 waves; wave (g=wave>>1, h=wave&1) owns rows
// [32g,32g+32) x cols [64h,64h+64): acc[2][4], 32 AGPR/wave.
// flags: 1 = relu, 2 = fp16 output (else bf16)

struct GemmJob {
    const ushort_t* A1; const ushort_t* W1; int K1;
    const ushort_t* A2; const ushort_t* W2; int K2;
    const ushort_t* Add; const float* bias;
    void* C; int M; int flags;
};

struct GatherJob {        // D=256 rows
    const ushort_t* X; const int* rowptr; const int* cnt; const int* col;
    ushort_t* out; int N;
};

struct Gather128Job {     // D=128 rows
    const ushort_t* X; const int* rowptr; const int* cnt; const int* col;
    ushort_t* out; int N;
};

__device__ __forceinline__ void gemm_body(const GemmJob& jb, int bid)
{
    __shared__ ushort_t As[64][40];
    __shared__ ushort_t Bs[128][40];
    const int tid = threadIdx.x;
    const int M = jb.M;

    // ---- XCD-paired swizzle: bid -> (rowblk, colblk), 64-row blocks ----
    const int nx = (M + 63) >> 6;           // row-blocks
    const int nx8 = nx & ~7;                // swizzled region (multiple of 8)
    int rowblk, colblk;
    if (bid < nx8 * 2) {
        const int group = bid >> 4;         // 16 blocks per group
        const int xcd = bid & 7;
        const int half = (bid >> 3) & 1;
        rowblk = group * 8 + xcd;
        colblk = half;
    } else {
        const int r = bid - nx8 * 2;
        rowblk = nx8 + (r >> 1);
        colblk = r & 1;
    }
    const int row0 = rowblk * 64, col0 = colblk * 128;

    const int wave = tid >> 6, lane = tid & 63;
    const int wrow = (wave >> 1) * 32;      // 2 row-groups of 32
    const int wcol = (wave & 1) * 64;       // 2 col-groups of 64
    const int m16 = lane & 15, quad = lane >> 4;
    const int sr = tid >> 2;                // staging row 0..63
    const int skc = (tid & 3) * 8;          // k-chunk (ushorts): 0,8,16,24

    float4v acc[2][4];
#pragma unroll
    for (int i = 0; i < 2; i++)
#pragma unroll
        for (int j = 0; j < 4; j++) acc[i][j] = (float4v){0.f, 0.f, 0.f, 0.f};

#pragma unroll 1
    for (int pass = 0; pass < 2; pass++) {
        const ushort_t* A = pass ? jb.A2 : jb.A1;
        const ushort_t* W = pass ? jb.W2 : jb.W1;
        const int K = pass ? jb.K2 : jb.K1;
        if (!A) break;
        const int gra = row0 + sr;
        const bool oka = gra < M;
        const ushort_t* Ap = A + (size_t)gra * K + skc;
        const ushort_t* Wp0 = W + (size_t)(col0 + sr) * K + skc;
        const ushort_t* Wp1 = W + (size_t)(col0 + 64 + sr) * K + skc;

        // preload tile 0
        uint4 a0 = make_uint4(0, 0, 0, 0);
        if (oka) a0 = *(const uint4*)Ap;
        uint4 b0 = *(const uint4*)Wp0;
        uint4 b1 = *(const uint4*)Wp1;

        for (int k0 = 0; k0 < K; k0 += 32) {
            __syncthreads();                 // prev iter done reading LDS
            *(uint4*)&As[sr][skc] = a0;
            *(uint4*)&Bs[sr][skc] = b0;
            *(uint4*)&Bs[64 + sr][skc] = b1;
            __syncthreads();                 // LDS ready
            if (k0 + 32 < K) {               // prefetch tile k+1
                a0 = make_uint4(0, 0, 0, 0);
                if (oka) a0 = *(const uint4*)(Ap + k0 + 32);
                b0 = *(const uint4*)(Wp0 + k0 + 32);
                b1 = *(const uint4*)(Wp1 + k0 + 32);
            }
            short8 af[2], bf[4];
#pragma unroll
            for (int i = 0; i < 2; i++)
                af[i] = *(const short8*)&As[wrow + i * 16 + m16 - wrow][quad * 8 + (wrow ? 0 : 0)];
            // NOTE: wrow covers rows 0..63 via wave>>1; direct index:
#pragma unroll
            for (int i = 0; i < 2; i++)
                af[i] = *(const short8*)&As[wrow + i * 16 + m16 - (wrow ? wrow : 0) + (wrow ? wrow : 0) - wrow + wrow][quad * 8];
#pragma unroll
            for (int i = 0; i < 2; i++)
                af[i] = *(const short8*)&As[wrow + i * 16 + m16][quad * 8];
#pragma unroll
            for (int j = 0; j < 4; j++)
                bf[j] = *(const short8*)&Bs[wcol + j * 16 + m16][quad * 8];
#pragma unroll
            for (int i = 0; i < 2; i++)
#pragma unroll
                for (int j = 0; j < 4; j++)
                    acc[i][j] = __builtin_amdgcn_mfma_f32_16x16x32_bf16(
                        af[i], bf[j], acc[i][j], 0, 0, 0);
        }
    }

    const bool relu = jb.flags & 1, f16out = jb.flags & 2;
#pragma unroll
    for (int i = 0; i < 2; i++) {
        const int rbase = row0 + wrow + i * 16 + quad * 4;
#pragma unroll
        for (int r = 0; r < 4; r++) {
            const int row = rbase + r;
            if (row >= M) continue;
#pragma unroll
            for (int j = 0; j < 4; j++) {
                const int col = col0 + wcol + j * 16 + m16;
                float v = acc[i][j][r];
                if (jb.Add) v += bf2f((unsigned int)jb.Add[(size_t)row * 256 + col]);
                if (jb.bias) v += jb.bias[col];
                if (relu) v = fmaxf(v, 0.f);
                if (f16out) ((_Float16*)jb.C)[(size_t)row * 256 + col] = (_Float16)v;
                else ((ushort_t*)jb.C)[(size_t)row * 256 + col] = f2bf(v);
            }
        }
    }
}

// ---------------- gather mean bodies (bf16 rows, fp32 accum, ILP-4) --------
#define UNPACK_ADD(acc, v) \
    acc[0] += bf2f(v.x & 0xffff); acc[1] += bf2f(v.x >> 16); \
    acc[2] += bf2f(v.y & 0xffff); acc[3] += bf2f(v.y >> 16); \
    acc[4] += bf2f(v.z & 0xffff); acc[5] += bf2f(v.z >> 16); \
    acc[6] += bf2f(v.w & 0xffff); acc[7] += bf2f(v.w >> 16);

// D=256: 512 threads, 16 nodes/block, 32 lanes per node (8 cols each).
__device__ __forceinline__ void gather_body(const GatherJob& g, int gb)
{
    const int node = gb * 16 + (threadIdx.x >> 5);
    const int c = (threadIdx.x & 31) * 8;
    if (node >= g.N) return;
    const int beg = g.rowptr[node];
    const int deg = g.cnt[node];
    const int end = beg + deg;
    const ushort_t* __restrict__ X = g.X;
    const int* __restrict__ col = g.col;
    float a[8] = {0, 0, 0, 0, 0, 0, 0, 0};
    float b[8] = {0, 0, 0, 0, 0, 0, 0, 0};
    int i = beg;
    for (; i + 3 < end; i += 4) {
        const int c0 = col[i], c1 = col[i + 1], c2 = col[i + 2], c3 = col[i + 3];
        uint4 v0 = *(const uint4*)&X[(size_t)c0 * 256 + c];
        uint4 v1 = *(const uint4*)&X[(size_t)c1 * 256 + c];
        uint4 v2 = *(const uint4*)&X[(size_t)c2 * 256 + c];
        uint4 v3 = *(const uint4*)&X[(size_t)c3 * 256 + c];
        UNPACK_ADD(a, v0) UNPACK_ADD(b, v1) UNPACK_ADD(a, v2) UNPACK_ADD(b, v3)
    }
    for (; i + 1 < end; i += 2) {
        uint4 v0 = *(const uint4*)&X[(size_t)col[i] * 256 + c];
        uint4 v1 = *(const uint4*)&X[(size_t)col[i + 1] * 256 + c];
        UNPACK_ADD(a, v0) UNPACK_ADD(b, v1)
    }
    if (i < end) {
        uint4 v0 = *(const uint4*)&X[(size_t)col[i] * 256 + c];
        UNPACK_ADD(a, v0)
    }
    float inv = 1.f / fmaxf((float)deg, 1.f);
    uint4 o;
    o.x = (unsigned int)f2bf((a[0] + b[0]) * inv) | ((unsigned int)f2bf((a[1] + b[1]) * inv) << 16);
    o.y = (unsigned int)f2bf((a[2] + b[2]) * inv) | ((unsigned int)f2bf((a[3] + b[3]) * inv) << 16);
    o.z = (unsigned int)f2bf((a[4] + b[4]) * inv) | ((unsigned int)f2bf((a[5] + b[5]) * inv) << 16);
    o.w = (unsigned int)f2bf((a[6] + b[6]) * inv) | ((unsigned int)f2bf((a[7] + b[7]) * inv) << 16);
    *(uint4*)&g.out[(size_t)node * 256 + c] = o;
}

// D=128: 512 threads, 32 nodes/block, 16 lanes per node (8 cols each).
__device__ __forceinline__ void gather128_body(const Gather128Job& g, int gb)
{
    const int node = gb * 32 + (threadIdx.x >> 4);
    const int c = (threadIdx.x & 15) * 8;
    if (node >= g.N) return;
    const int beg = g.rowptr[node];
    const int deg = g.cnt[node];
    const int end = beg + deg;
    const ushort_t* __restrict__ X = g.X;
    const int* __restrict__ col = g.col;
    float a[8] = {0, 0, 0, 0, 0, 0, 0, 0};
    float b[8] = {0, 0, 0, 0, 0, 0, 0, 0};
    int i = beg;
    for (; i + 3 < end; i += 4) {
        const int c0 = col[i], c1 = col[i + 1], c2 = col[i + 2], c3 = col[i + 3];
        uint4 v0 = *(const uint4*)&X[(size_t)c0 * 128 + c];
        uint4 v1 = *(const uint4*)&X[(size_t)c1 * 128 + c];
        uint4 v2 = *(const uint4*)&X[(size_t)c2 * 128 + c];
        uint4 v3 = *(const uint4*)&X[(size_t)c3 * 128 + c];
        UNPACK_ADD(a, v0) UNPACK_ADD(b, v1) UNPACK_ADD(a, v2) UNPACK_ADD(b, v3)
    }
    for (; i + 1 < end; i += 2) {
        uint4 v0 = *(const uint4*)&X[(size_t)col[i] * 128 + c];
        uint4 v1 = *(const uint4*)&X[(size_t)col[i + 1] * 128 + c];
        UNPACK_ADD(a, v0) UNPACK_ADD(b, v1)
    }
    if (i < end) {
        uint4 v0 = *(const uint4*)&X[(size_t)col[i] * 128 + c];
        UNPACK_ADD(a, v0)
    }
    float inv = 1.f / fmaxf((float)deg, 1.f);
    uint4 o;
    o.x = (unsigned int)f2bf((a[0] + b[0]) * inv) | ((unsigned int)f2bf((a[1] + b[1]) * inv) << 16);
    o.y = (unsigned int)f2bf((a[2] + b[2]) * inv) | ((unsigned int)f2bf((a[3] + b[3]) * inv) << 16);
    o.z = (unsigned int)f2bf((a[4] + b[4]) * inv) | ((unsigned int)f2bf((a[5] + b[5]) * inv) << 16);
    o.w = (unsigned int)f2bf((a[6] + b[6]) * inv) | ((unsigned int)f2bf((a[7] + b[7]) * inv) << 16);
    *(uint4*)&g.out[(size_t)node * 128 + c] = o;
}

// --------------------------- fused launch shells ---------------------------
__global__ __launch_bounds__(256) void gemm_gemm_kernel(GemmJob a, int ablocks,
                                                        GemmJob b)
{
    const int bid = blockIdx.x;
    if (bid < ablocks) gemm_body(a, bid);
    else gemm_body(b, bid - ablocks);
}

__global__ __launch_bounds__(512) void gather_g128_kernel(GatherJob a, int ablocks,
                                                          Gather128Job b)
{
    const int bid = blockIdx.x;
    if (bid < ablocks) gather_body(a, bid);
    else gather128_body(b, bid - ablocks);
}

__global__ __launch_bounds__(512) void gather_gather_kernel(GatherJob a, int ablocks,
                                                            GatherJob b)
{
    const int bid = blockIdx.x;
    if (bid < ablocks) gather_body(a, bid);
    else gather_body(b, bid - ablocks);
}

// ----------------------- ILP-4 fp32 -> bf16 convert ------------------------
struct CvtJobs {
    const float* src[14];
    ushort_t* dst[14];
    int n4[14];
    int cnt;
};

__global__ __launch_bounds__(256) void cvt_kernel(CvtJobs jb, int nchunks)
{
    const int t = threadIdx.x;
#pragma unroll 1
    for (int ch = blockIdx.x; ch < nchunks; ch += gridDim.x) {
        int idx = ch << 10;                // first float4 of this chunk
        int k = 0;
        while (idx >= jb.n4[k]) { idx -= jb.n4[k]; ++k; }   // uniform search
        const float4* __restrict__ s = (const float4*)jb.src[k];
        ushort_t* __restrict__ d = jb.dst[k];
        const int base = idx + t;
        float4 v0 = s[base];
        float4 v1 = s[base + 256];
        float4 v2 = s[base + 512];
        float4 v3 = s[base + 768];
        uint2 o0, o1, o2, o3;
        o0.x = (unsigned int)f2bf(v0.x) | ((unsigned int)f2bf(v0.y) << 16);
        o0.y = (unsigned int)f2bf(v0.z) | ((unsigned int)f2bf(v0.w) << 16);
        o1.x = (unsigned int)f2bf(v1.x) | ((unsigned int)f2bf(v1.y) << 16);
        o1.y = (unsigned int)f2bf(v1.z) | ((unsigned int)f2bf(v1.w) << 16);
        o2.x = (unsigned int)f2bf(v2.x) | ((unsigned int)f2bf(v2.y) << 16);
        o2.y = (unsigned int)f2bf(v2.z) | ((unsigned int)f2bf(v2.w) << 16);
        o3.x = (unsigned int)f2bf(v3.x) | ((unsigned int)f2bf(v3.y) << 16);
        o3.y = (unsigned int)f2bf(v3.z) | ((unsigned int)f2bf(v3.w) << 16);
        *(uint2*)(d + (size_t)base * 4) = o0;
        *(uint2*)(d + (size_t)(base + 256) * 4) = o1;
        *(uint2*)(d + (size_t)(base + 512) * 4) = o2;
        *(uint2*)(d + (size_t)(base + 768) * 4) = o3;
    }
}

// ----------------------- edge-degree count (ILP-4) -------------------------
__global__ __launch_bounds__(256) void count_kernel(
    const int* __restrict__ src, const int* __restrict__ dst,
    int* __restrict__ cnt_s, int* __restrict__ cnt_t, int E)
{
    const int base = blockIdx.x * 1024 + threadIdx.x;
    const int e0 = base, e1 = base + 256, e2 = base + 512, e3 = base + 768;
    int s0 = 0, s1 = 0, s2 = 0, s3 = 0;
    int d0 = 0, d1 = 0, d2 = 0, d3 = 0;
    if (e0 < E) { s0 = src[e0]; d0 = dst[e0]; }
    if (e1 < E) { s1 = src[e1]; d1 = dst[e1]; }
    if (e2 < E) { s2 = src[e2]; d2 = dst[e2]; }
    if (e3 < E) { s3 = src[e3]; d3 = dst[e3]; }
    if (e0 < E) { atomicAdd(&cnt_s[s0], 1); atomicAdd(&cnt_t[d0], 1); }
    if (e1 < E) { atomicAdd(&cnt_s[s1], 1); atomicAdd(&cnt_t[d1], 1); }
    if (e2 < E) { atomicAdd(&cnt_s[s2], 1); atomicAdd(&cnt_t[d2], 1); }
    if (e3 < E) { atomicAdd(&cnt_s[s3], 1); atomicAdd(&cnt_t[d3], 1); }
}

// -------------- decoder weight folding (one fused kernel) ------------------
__global__ __launch_bounds__(256) void fold_kernel(
    const float* __restrict__ Wd1, const float* __restrict__ bd1,
    const float* __restrict__ Wlin_s, const float* __restrict__ blin_s,
    const float* __restrict__ Wlin_t, const float* __restrict__ blin_t,
    float* __restrict__ Wc_s, float* __restrict__ Wc_t,
    float* __restrict__ bu, float* __restrict__ bv)
{
    const int b = blockIdx.x, t = threadIdx.x;
    if (b < 256) {
        float s = 0.f;
        for (int k = 0; k < 256; k++) s += Wd1[b * 512 + k] * Wlin_s[k * 256 + t];
        Wc_s[b * 256 + t] = s;
    } else if (b < 512) {
        const int h = b - 256;
        float s = 0.f;
        for (int k = 0; k < 256; k++) s += Wd1[h * 512 + 256 + k] * Wlin_t[k * 256 + t];
        Wc_t[h * 256 + t] = s;
    } else {
        float su = 0.f, sv = 0.f;
        for (int k = 0; k < 256; k++) {
            su += Wd1[t * 512 + k] * blin_s[k];
            sv += Wd1[t * 512 + 256 + k] * blin_t[k];
        }
        bu[t] = bd1[t] + su;
        bv[t] = sv;
    }
}

// --------------------------- CSR build -------------------------------------
__global__ __launch_bounds__(256) void psum_kernel(
    const int* __restrict__ cnt_s, const int* __restrict__ cnt_t,
    int* __restrict__ bsum_s, int* __restrict__ bsum_t, int nbS)
{
    const bool isS = (int)blockIdx.x < nbS;
    const int blk = isS ? blockIdx.x : blockIdx.x - nbS;
    const int N = isS ? NS : NT;
    const int* cnt = isS ? cnt_s : cnt_t;
    int* bsum = isS ? bsum_s : bsum_t;
    __shared__ int sdata[256];
    const int t = threadIdx.x;
    const int base = blk * 1024;
    int s = 0;
    for (int i = t; i < 1024; i += 256) {
        int idx = base + i;
        s += (idx < N) ? cnt[idx] : 0;
    }
    sdata[t] = s; __syncthreads();
    for (int off = 128; off > 0; off >>= 1) {
        if (t < off) sdata[t] += sdata[t + off];
        __syncthreads();
    }
    if (t == 0) bsum[blk] = sdata[0];
}

__global__ void sbsum_kernel(int* __restrict__ bsum_s, int* __restrict__ bsum_t,
                             int nbS, int nbT)
{
    if (threadIdx.x != 0) return;
    int* b = blockIdx.x ? bsum_t : bsum_s;
    int nb = blockIdx.x ? nbT : nbS;
    int run = 0;
    for (int i = 0; i < nb; i++) { int v = b[i]; b[i] = run; run += v; }
}

__global__ __launch_bounds__(256) void sblock_kernel(
    const int* __restrict__ cnt_s, const int* __restrict__ cnt_t,
    const int* __restrict__ bsum_s, const int* __restrict__ bsum_t,
    int* __restrict__ rowptr_s, int* __restrict__ rowptr_t, int nbS)
{
    const bool isS = (int)blockIdx.x < nbS;
    const int blk = isS ? blockIdx.x : blockIdx.x - nbS;
    const int N = isS ? NS : NT;
    const int* cnt = isS ? cnt_s : cnt_t;
    const int* bsum = isS ? bsum_s : bsum_t;
    int* rowptr = isS ? rowptr_s : rowptr_t;
    __shared__ int sc[256];
    const int t = threadIdx.x;
    const int base = blk * 1024 + t * 4;
    int v[4]; int s = 0;
#pragma unroll
    for (int j = 0; j < 4; j++) {
        int idx = base + j;
        v[j] = (idx < N) ? cnt[idx] : 0;
        s += v[j];
    }
    sc[t] = s; __syncthreads();
    for (int off = 1; off < 256; off <<= 1) {
        int add = (t >= off) ? sc[t - off] : 0;
        __syncthreads();
        sc[t] += add;
        __syncthreads();
    }
    int excl = sc[t] - s + bsum[blk];
#pragma unroll
    for (int j = 0; j < 4; j++) {
        int idx = base + j;
        if (idx < N) rowptr[idx] = excl;
        if (idx == N - 1) rowptr[N] = excl + v[j];
        excl += v[j];
    }
}

__global__ void binit_kernel(const int* __restrict__ rowptr_t,
                             const int* __restrict__ rowptr_s,
                             int* __restrict__ gcur_t, int* __restrict__ gcur_s)
{
    int t = threadIdx.x;
    if (t < NB_T) gcur_t[t] = rowptr_t[t << SH_T];
    if (t < NB_S) gcur_s[t] = rowptr_s[t << SH_S];
}

__global__ __launch_bounds__(256) void binA_kernel(
    const int* __restrict__ key, const int* __restrict__ val, int E,
    int nbins, int shift, int vbits,
    int* __restrict__ gcur, unsigned* __restrict__ stg)
{
    __shared__ unsigned bins[NB_S * BIN_CAP];
    __shared__ int lcnt[NB_S], gbase[NB_S];
    const int tid = threadIdx.x;
    const int base = blockIdx.x * CHUNK;
    for (int i = tid; i < nbins; i += 256) lcnt[i] = 0;
    __syncthreads();
    const unsigned lowmask = (1u << shift) - 1u;
#pragma unroll
    for (int k = 0; k < CHUNK / 256; k++) {
        int e = base + k * 256 + tid;
        if (e < E) {
            int kk = key[e];
            int b = kk >> shift;
            unsigned pk = (((unsigned)kk & lowmask) << vbits) | (unsigned)val[e];
            int c = atomicAdd(&lcnt[b], 1);
            if (c < BIN_CAP) bins[b * BIN_CAP + c] = pk;
            else { int p = atomicAdd(&gcur[b], 1); stg[p] = pk; }
        }
    }
    __syncthreads();
    if (tid < nbins) gbase[tid] = atomicAdd(&gcur[tid], min(lcnt[tid], BIN_CAP));
    __syncthreads();
    for (int b = 0; b < nbins; b++) {
        int c = min(lcnt[b], BIN_CAP);
        for (int i = tid; i < c; i += 256) stg[gbase[b] + i] = bins[b * BIN_CAP + i];
    }
}

__global__ __launch_bounds__(256) void binB_kernel(
    const unsigned* __restrict__ stg, const int* __restrict__ rowptr,
    int N, int node_per, int vbits, int* __restrict__ colout)
{
    __shared__ int cur[1024];
    const int tid = threadIdx.x;
    const int node0 = blockIdx.x * node_per;
    const int nn = min(node_per, N - node0);
    for (int i = tid; i < nn; i += 256) cur[i] = rowptr[node0 + i];
    const int estart = rowptr[node0];
    const int eend = rowptr[node0 + nn];
    __syncthreads();
    const unsigned vmask = (1u << vbits) - 1u;
    for (int i = estart + tid; i < eend; i += 256) {
        unsigned v = stg[i];
        int kl = (int)(v >> vbits);
        int pos = atomicAdd(&cur[kl], 1);
        colout[pos] = (int)(v & vmask);
    }
}

// ------------------------- per-edge score (fp16 U/V) -----------------------
__global__ __launch_bounds__(256) void edge_score_kernel(
    const _Float16* __restrict__ U, const _Float16* __restrict__ V,
    const int* __restrict__ ls, const int* __restrict__ ld,
    const float* __restrict__ Wd2, const float* __restrict__ bd2,
    float* __restrict__ out, int EL)
{
    const int l32 = threadIdx.x & 31;
    const int e = blockIdx.x * 8 + (threadIdx.x >> 5);
    if (e >= EL) return;
    const int c = l32 * 8;
    half8v u = *(const half8v*)&U[(size_t)ls[e] * 256 + c];
    half8v v = *(const half8v*)&V[(size_t)ld[e] * 256 + c];
    float4 w0 = *(const float4*)&Wd2[c];
    float4 w1 = *(const float4*)&Wd2[c + 4];
    float s = fmaxf((float)u[0] + (float)v[0], 0.f) * w0.x
            + fmaxf((float)u[1] + (float)v[1], 0.f) * w0.y
            + fmaxf((float)u[2] + (float)v[2], 0.f) * w0.z
            + fmaxf((float)u[3] + (float)v[3], 0.f) * w0.w
            + fmaxf((float)u[4] + (float)v[4], 0.f) * w1.x
            + fmaxf((float)u[5] + (float)v[5], 0.f) * w1.y
            + fmaxf((float)u[6] + (float)v[6], 0.f) * w1.z
            + fmaxf((float)u[7] + (float)v[7], 0.f) * w1.w;
#pragma unroll
    for (int m = 16; m >= 1; m >>= 1) s += __shfl_xor(s, m, 64);
    if (l32 == 0) out[e] = s + bd2[0];
}

// ---------------------------------------------------------------------------
extern "C" void kernel_launch(void* const* d_in, const int* in_sizes, int n_in,
                              void* d_out, int out_size, void* d_ws, size_t ws_size,
                              hipStream_t stream)
{
    const float* x_sotu  = (const float*)d_in[0];
    const float* x_taxon = (const float*)d_in[1];
    const int* edge_src  = (const int*)d_in[2];
    const int* edge_dst  = (const int*)d_in[3];
    const int* label_src = (const int*)d_in[4];
    const int* label_dst = (const int*)d_in[5];
    const float* Wl1_st = (const float*)d_in[6];
    const float* bl1_st = (const float*)d_in[7];
    const float* Wr1_st = (const float*)d_in[8];
    const float* Wl1_ts = (const float*)d_in[9];
    const float* bl1_ts = (const float*)d_in[10];
    const float* Wr1_ts = (const float*)d_in[11];
    const float* Wl2_st = (const float*)d_in[12];
    const float* bl2_st = (const float*)d_in[13];
    const float* Wr2_st = (const float*)d_in[14];
    const float* Wl2_ts = (const float*)d_in[15];
    const float* bl2_ts = (const float*)d_in[16];
    const float* Wr2_ts = (const float*)d_in[17];
    const float* Wlin_s = (const float*)d_in[18];
    const float* blin_s = (const float*)d_in[19];
    const float* Wlin_t = (const float*)d_in[20];
    const float* blin_t = (const float*)d_in[21];
    const float* Wd1 = (const float*)d_in[22];
    const float* bd1 = (const float*)d_in[23];
    const float* Wd2 = (const float*)d_in[24];
    const float* bd2 = (const float*)d_in[25];

    // -------- workspace layout --------
    int* wi = (int*)d_ws;
    size_t io = 0;
    int* cnt_s   = wi + io; io += NS;
    int* cnt_t   = wi + io; io += NT;
    int* rowptr_s = wi + io; io += NS + 8;
    int* rowptr_t = wi + io; io += NT + 8;
    int* col_s   = wi + io; io += E_EDGES;
    int* col_t   = wi + io; io += E_EDGES;
    unsigned* stg_s = (unsigned*)(wi + io); io += E_EDGES;
    unsigned* stg_t = (unsigned*)(wi + io); io += E_EDGES;
    int* bsum_s  = wi + io; io += 128;
    int* bsum_t  = wi + io; io += 128;
    int* gcur_t  = wi + io; io += 128;
    int* gcur_s  = wi + io; io += 128;
    io = (io + 63) & ~(size_t)63;

    ushort_t* wb = (ushort_t*)(wi + io);
    size_t bo = 0;
    ushort_t* m_s  = wb + bo; bo += (size_t)NS * H;   // mxt/mh gather out; U overlays
    ushort_t* h1_s = wb + bo; bo += (size_t)NS * H;
    ushort_t* m_t  = wb + bo; bo += (size_t)NT * H;   // V (fp16) overlays m_t
    ushort_t* h1_t = wb + bo; bo += (size_t)NT * H;
    ushort_t* h2_s = wb + bo; bo += (size_t)NS * H;
    ushort_t* h2_t = wb + bo; bo += (size_t)NT * H;
    ushort_t* xs_b = wb + bo; bo += (size_t)NS * DS;
    ushort_t* xt_b = wb + bo; bo += (size_t)NT * DT;
    ushort_t* wb_l1st = wb + bo; bo += H * DS;
    ushort_t* wb_r1st = wb + bo; bo += H * DT;
    ushort_t* wb_l1ts = wb + bo; bo += H * DT;
    ushort_t* wb_r1ts = wb + bo; bo += H * DS;
    ushort_t* wb_l2st = wb + bo; bo += H * H;
    ushort_t* wb_r2st = wb + bo; bo += H * H;
    ushort_t* wb_l2ts = wb + bo; bo += H * H;
    ushort_t* wb_r2ts = wb + bo; bo += H * H;
    ushort_t* wcb_s   = wb + bo; bo += H * H;
    ushort_t* wcb_t   = wb + bo; bo += H * H;
    bo = (bo + 7) & ~(size_t)7;

    float* wf = (float*)(wb + bo);
    size_t fo = 0;
    float* Wc_s = wf + fo; fo += H * H;
    float* Wc_t = wf + fo; fo += H * H;
    float* bu   = wf + fo; fo += 256;
    float* bv   = wf + fo; fo += 256;

    _Float16* U = (_Float16*)m_s;
    _Float16* V = (_Float16*)m_t;

    const dim3 blk(256);
    const dim3 blk512(512);
    auto mgn = [](int M) { return ((M + 63) / 64) * 2; };     // gemm blocks (64-row)
    auto g256n = [](int N) { return (N + 15) / 16; };         // D=256 gather blocks
    auto g128n = [](int N) { return (N + 31) / 32; };         // D=128 gather blocks
    const int nbS = (NS + 1023) / 1024;   // 98
    const int nbT = (NT + 1023) / 1024;   // 20
    const int nA = (E_EDGES + CHUNK - 1) / CHUNK;

    // ---- decoder weight folding ----
    fold_kernel<<<513, blk, 0, stream>>>(Wd1, bd1, Wlin_s, blin_s, Wlin_t, blin_t,
                                         Wc_s, Wc_t, bu, bv);

    // ---- edge-degree count (ILP-4) ----
    hipMemsetAsync(cnt_s, 0, (size_t)(NS + NT) * sizeof(int), stream);
    count_kernel<<<(E_EDGES + 1023) / 1024, blk, 0, stream>>>(
        edge_src, edge_dst, cnt_s, cnt_t, E_EDGES);

    // ---- ILP-4 fp32->bf16 convert ----
    {
        CvtJobs jb; int c = 0, total4 = 0;
        auto addj = [&](const float* s, ushort_t* d, int n) {
            jb.src[c] = s; jb.dst[c] = d; jb.n4[c] = n / 4; total4 += n / 4; c++;
        };
        addj(x_sotu, xs_b, NS * DS);
        addj(x_taxon, xt_b, NT * DT);
        addj(Wl1_st, wb_l1st, H * DS);
        addj(Wr1_st, wb_r1st, H * DT);
        addj(Wl1_ts, wb_l1ts, H * DT);
        addj(Wr1_ts, wb_r1ts, H * DS);
        addj(Wl2_st, wb_l2st, H * H);
        addj(Wr2_st, wb_r2st, H * H);
        addj(Wl2_ts, wb_l2ts, H * H);
        addj(Wr2_ts, wb_r2ts, H * H);
        addj(Wc_s, wcb_s, H * H);
        addj(Wc_t, wcb_t, H * H);
        jb.cnt = c;
        const int nchunks = total4 >> 10;  // every n4 is a multiple of 1024
        const int cvb = nchunks < CVT_BLOCKS ? nchunks : CVT_BLOCKS;
        cvt_kernel<<<cvb, blk, 0, stream>>>(jb, nchunks);
    }

    // ---- CSR build: scan -> binned two-pass fill ----
    psum_kernel<<<nbS + nbT, blk, 0, stream>>>(cnt_s, cnt_t, bsum_s, bsum_t, nbS);
    sbsum_kernel<<<2, 64, 0, stream>>>(bsum_s, bsum_t, nbS, nbT);
    sblock_kernel<<<nbS + nbT, blk, 0, stream>>>(cnt_s, cnt_t, bsum_s, bsum_t,
                                                 rowptr_s, rowptr_t, nbS);
    binit_kernel<<<1, blk, 0, stream>>>(rowptr_t, rowptr_s, gcur_t, gcur_s);
    binA_kernel<<<nA, blk, 0, stream>>>(edge_dst, edge_src, E_EDGES,
                                        NB_T, SH_T, VB_T, gcur_t, stg_t);
    binA_kernel<<<nA, blk, 0, stream>>>(edge_src, edge_dst, E_EDGES,
                                        NB_S, SH_S, VB_S, gcur_s, stg_s);
    binB_kernel<<<NB_T, blk, 0, stream>>>(stg_t, rowptr_t, NT, 1 << SH_T, VB_T, col_t);
    binB_kernel<<<NB_S, blk, 0, stream>>>(stg_s, rowptr_s, NS, 1 << SH_S, VB_S, col_s);

    // ---- layer 1: aggregate-then-project ----
    {   // m_t = gmean(xs) [D=256]  ||  mxt_s = gmean(xt) [D=128, in m_s slot]
        GatherJob a{xs_b, rowptr_t, cnt_t, col_t, m_t, NT};
        Gather128Job b{xt_b, rowptr_s, cnt_s, col_s, m_s, NS};
        const int ab = g256n(NT);
        gather_g128_kernel<<<ab + g128n(NS), blk512, 0, stream>>>(a, ab, b);
    }
    {   // h1_s = relu(xs@Wr1_ts' + mxt_s@Wl1_ts' + b)  ||  h1_t = relu(...)
        GemmJob a{xs_b, wb_r1ts, DS, m_s, wb_l1ts, DT, nullptr, bl1_ts, h1_s, NS, 1};
        GemmJob b{m_t, wb_l1st, H, xt_b, wb_r1st, DT, nullptr, bl1_st, h1_t, NT, 1};
        const int ab = mgn(NS);
        gemm_gemm_kernel<<<ab + mgn(NT), blk, 0, stream>>>(a, ab, b);
    }

    // ---- layer 2: aggregate-then-project ----
    {   // m_t = gmean(h1_s) [D=256]  ||  mh_s = gmean(h1_t) [D=256, m_s slot]
        GatherJob a{h1_s, rowptr_t, cnt_t, col_t, m_t, NT};
        GatherJob b{h1_t, rowptr_s, cnt_s, col_s, m_s, NS};
        const int ab = g256n(NT);
        gather_gather_kernel<<<ab + g256n(NS), blk512, 0, stream>>>(a, ab, b);
    }
    {   // h2_s = relu(h1_s@Wr2_ts' + mh_s@Wl2_ts' + b)  ||  h2_t = relu(...)
        GemmJob a{h1_s, wb_r2ts, H, m_s, wb_l2ts, H, nullptr, bl2_ts, h2_s, NS, 1};
        GemmJob b{m_t, wb_l2st, H, h1_t, wb_r2st, H, nullptr, bl2_st, h2_t, NT, 1};
        const int ab = mgn(NS);
        gemm_gemm_kernel<<<ab + mgn(NT), blk, 0, stream>>>(a, ab, b);
    }

    // ---- decoder: U (NS) || V (NT) node potentials (fp16 out) ----
    {
        GemmJob a{h2_s, wcb_s, H, nullptr, nullptr, 0, nullptr, bu, U, NS, 2};
        GemmJob b{h2_t, wcb_t, H, nullptr, nullptr, 0, nullptr, bv, V, NT, 2};
        const int ab = mgn(NS);
        gemm_gemm_kernel<<<ab + mgn(NT), blk, 0, stream>>>(a, ab, b);
    }
    edge_score_kernel<<<(EL_EDGES + 7) / 8, blk, 0, stream>>>(
        U, V, label_src, label_dst, Wd2, bd2, (float*)d_out, EL_EDGES);
}

// Round 11
// 744.263 us; speedup vs baseline: 1.2447x; 1.0510x over previous
//
#include <hip/hip_runtime.h>

// ---------------------------------------------------------------------------
// Hetero GraphSAGE (2 layers) + edge decoder.
// R1: CSR-gather. R5: bf16 MFMA GEMMs. R6: fp16 U/V. R8: binned CSR fill.
// R10: XCD swizzle. R12: 32x64-wave-tile GEMM. R15: dispatch fusion.
// R21: aggregate-then-project — 926 -> 795us.
// R22: 64x128 GEMM tile (256 thr) + gather ILP-4 — 795 -> 782. Gather
//   UNCHANGED at 106us/3.8TB/s => fabric-BW-bound (structural floor:
//   random 512B rows, scatter alternative costs more in atomics).
// R23 (this): collapse the ~145us serial prologue via independence fusion:
//   [fold || count], scan, [cvt || binA_t], [binA_s || binB_t], binB_s.
//   Saves ~45us of serialization. Cleaned R22 dead code in gemm_body.
// ---------------------------------------------------------------------------

constexpr int NS = 100000, NT = 20000;
constexpr int E_EDGES = 800000, EL_EDGES = 200000;
constexpr int DS = 256, DT = 128, H = 256;

constexpr int NB_T = 79, SH_T = 8, VB_T = 17;
constexpr int NB_S = 98, SH_S = 10, VB_S = 15;
constexpr int BIN_CAP = 96, CHUNK = 2048;
constexpr int CVT_BLOCKS = 2048;

typedef __attribute__((ext_vector_type(8))) short short8;
typedef __attribute__((ext_vector_type(4))) float float4v;
typedef __attribute__((ext_vector_type(8))) _Float16 half8v;
typedef unsigned short ushort_t;

__device__ __forceinline__ float bf2f(unsigned int u) {
    union { unsigned int i; float f; } x; x.i = u << 16; return x.f;
}
__device__ __forceinline__ unsigned short f2bf(float f) {
    union { float f; unsigned int i; } x; x.f = f;
    unsigned int r = x.i + 0x7FFFu + ((x.i >> 16) & 1u);   // RNE
    return (unsigned short)(r >> 16);
}

// --------------------------- MFMA GEMM body (R22) --------------------------
// C[M,256] = op( A1@W1^T [+ A2@W2^T] [+ bias] )
// 64x128 block tile, BK=32, LDS stride 40, XCD-paired swizzle, reg prefetch.
// 256 threads / 4 waves; wave (g=wave>>1, h=wave&1) owns rows
// [32g,32g+32) x cols [64h,64h+64): acc[2][4], 32 AGPR/wave.
// flags: 1 = relu, 2 = fp16 output (else bf16)

struct GemmJob {
    const ushort_t* A1; const ushort_t* W1; int K1;
    const ushort_t* A2; const ushort_t* W2; int K2;
    const ushort_t* Add; const float* bias;
    void* C; int M; int flags;
};

struct GatherJob {        // D=256 rows
    const ushort_t* X; const int* rowptr; const int* cnt; const int* col;
    ushort_t* out; int N;
};

struct Gather128Job {     // D=128 rows
    const ushort_t* X; const int* rowptr; const int* cnt; const int* col;
    ushort_t* out; int N;
};

__device__ __forceinline__ void gemm_body(const GemmJob& jb, int bid)
{
    __shared__ ushort_t As[64][40];
    __shared__ ushort_t Bs[128][40];
    const int tid = threadIdx.x;
    const int M = jb.M;

    // ---- XCD-paired swizzle: bid -> (rowblk, colblk), 64-row blocks ----
    const int nx = (M + 63) >> 6;           // row-blocks
    const int nx8 = nx & ~7;                // swizzled region (multiple of 8)
    int rowblk, colblk;
    if (bid < nx8 * 2) {
        const int group = bid >> 4;         // 16 blocks per group
        const int xcd = bid & 7;
        const int half = (bid >> 3) & 1;
        rowblk = group * 8 + xcd;
        colblk = half;
    } else {
        const int r = bid - nx8 * 2;
        rowblk = nx8 + (r >> 1);
        colblk = r & 1;
    }
    const int row0 = rowblk * 64, col0 = colblk * 128;

    const int wave = tid >> 6, lane = tid & 63;
    const int wrow = (wave >> 1) * 32;      // 2 row-groups of 32
    const int wcol = (wave & 1) * 64;       // 2 col-groups of 64
    const int m16 = lane & 15, quad = lane >> 4;
    const int sr = tid >> 2;                // staging row 0..63
    const int skc = (tid & 3) * 8;          // k-chunk (ushorts): 0,8,16,24

    float4v acc[2][4];
#pragma unroll
    for (int i = 0; i < 2; i++)
#pragma unroll
        for (int j = 0; j < 4; j++) acc[i][j] = (float4v){0.f, 0.f, 0.f, 0.f};

#pragma unroll 1
    for (int pass = 0; pass < 2; pass++) {
        const ushort_t* A = pass ? jb.A2 : jb.A1;
        const ushort_t* W = pass ? jb.W2 : jb.W1;
        const int K = pass ? jb.K2 : jb.K1;
        if (!A) break;
        const int gra = row0 + sr;
        const bool oka = gra < M;
        const ushort_t* Ap = A + (size_t)gra * K + skc;
        const ushort_t* Wp0 = W + (size_t)(col0 + sr) * K + skc;
        const ushort_t* Wp1 = W + (size_t)(col0 + 64 + sr) * K + skc;

        // preload tile 0
        uint4 a0 = make_uint4(0, 0, 0, 0);
        if (oka) a0 = *(const uint4*)Ap;
        uint4 b0 = *(const uint4*)Wp0;
        uint4 b1 = *(const uint4*)Wp1;

        for (int k0 = 0; k0 < K; k0 += 32) {
            __syncthreads();                 // prev iter done reading LDS
            *(uint4*)&As[sr][skc] = a0;
            *(uint4*)&Bs[sr][skc] = b0;
            *(uint4*)&Bs[64 + sr][skc] = b1;
            __syncthreads();                 // LDS ready
            if (k0 + 32 < K) {               // prefetch tile k+1
                a0 = make_uint4(0, 0, 0, 0);
                if (oka) a0 = *(const uint4*)(Ap + k0 + 32);
                b0 = *(const uint4*)(Wp0 + k0 + 32);
                b1 = *(const uint4*)(Wp1 + k0 + 32);
            }
            short8 af[2], bf[4];
#pragma unroll
            for (int i = 0; i < 2; i++)
                af[i] = *(const short8*)&As[wrow + i * 16 + m16][quad * 8];
#pragma unroll
            for (int j = 0; j < 4; j++)
                bf[j] = *(const short8*)&Bs[wcol + j * 16 + m16][quad * 8];
#pragma unroll
            for (int i = 0; i < 2; i++)
#pragma unroll
                for (int j = 0; j < 4; j++)
                    acc[i][j] = __builtin_amdgcn_mfma_f32_16x16x32_bf16(
                        af[i], bf[j], acc[i][j], 0, 0, 0);
        }
    }

    const bool relu = jb.flags & 1, f16out = jb.flags & 2;
#pragma unroll
    for (int i = 0; i < 2; i++) {
        const int rbase = row0 + wrow + i * 16 + quad * 4;
#pragma unroll
        for (int r = 0; r < 4; r++) {
            const int row = rbase + r;
            if (row >= M) continue;
#pragma unroll
            for (int j = 0; j < 4; j++) {
                const int col = col0 + wcol + j * 16 + m16;
                float v = acc[i][j][r];
                if (jb.Add) v += bf2f((unsigned int)jb.Add[(size_t)row * 256 + col]);
                if (jb.bias) v += jb.bias[col];
                if (relu) v = fmaxf(v, 0.f);
                if (f16out) ((_Float16*)jb.C)[(size_t)row * 256 + col] = (_Float16)v;
                else ((ushort_t*)jb.C)[(size_t)row * 256 + col] = f2bf(v);
            }
        }
    }
}

// ---------------- gather mean bodies (bf16 rows, fp32 accum, ILP-4) --------
#define UNPACK_ADD(acc, v) \
    acc[0] += bf2f(v.x & 0xffff); acc[1] += bf2f(v.x >> 16); \
    acc[2] += bf2f(v.y & 0xffff); acc[3] += bf2f(v.y >> 16); \
    acc[4] += bf2f(v.z & 0xffff); acc[5] += bf2f(v.z >> 16); \
    acc[6] += bf2f(v.w & 0xffff); acc[7] += bf2f(v.w >> 16);

// D=256: 512 threads, 16 nodes/block, 32 lanes per node (8 cols each).
__device__ __forceinline__ void gather_body(const GatherJob& g, int gb)
{
    const int node = gb * 16 + (threadIdx.x >> 5);
    const int c = (threadIdx.x & 31) * 8;
    if (node >= g.N) return;
    const int beg = g.rowptr[node];
    const int deg = g.cnt[node];
    const int end = beg + deg;
    const ushort_t* __restrict__ X = g.X;
    const int* __restrict__ col = g.col;
    float a[8] = {0, 0, 0, 0, 0, 0, 0, 0};
    float b[8] = {0, 0, 0, 0, 0, 0, 0, 0};
    int i = beg;
    for (; i + 3 < end; i += 4) {
        const int c0 = col[i], c1 = col[i + 1], c2 = col[i + 2], c3 = col[i + 3];
        uint4 v0 = *(const uint4*)&X[(size_t)c0 * 256 + c];
        uint4 v1 = *(const uint4*)&X[(size_t)c1 * 256 + c];
        uint4 v2 = *(const uint4*)&X[(size_t)c2 * 256 + c];
        uint4 v3 = *(const uint4*)&X[(size_t)c3 * 256 + c];
        UNPACK_ADD(a, v0) UNPACK_ADD(b, v1) UNPACK_ADD(a, v2) UNPACK_ADD(b, v3)
    }
    for (; i + 1 < end; i += 2) {
        uint4 v0 = *(const uint4*)&X[(size_t)col[i] * 256 + c];
        uint4 v1 = *(const uint4*)&X[(size_t)col[i + 1] * 256 + c];
        UNPACK_ADD(a, v0) UNPACK_ADD(b, v1)
    }
    if (i < end) {
        uint4 v0 = *(const uint4*)&X[(size_t)col[i] * 256 + c];
        UNPACK_ADD(a, v0)
    }
    float inv = 1.f / fmaxf((float)deg, 1.f);
    uint4 o;
    o.x = (unsigned int)f2bf((a[0] + b[0]) * inv) | ((unsigned int)f2bf((a[1] + b[1]) * inv) << 16);
    o.y = (unsigned int)f2bf((a[2] + b[2]) * inv) | ((unsigned int)f2bf((a[3] + b[3]) * inv) << 16);
    o.z = (unsigned int)f2bf((a[4] + b[4]) * inv) | ((unsigned int)f2bf((a[5] + b[5]) * inv) << 16);
    o.w = (unsigned int)f2bf((a[6] + b[6]) * inv) | ((unsigned int)f2bf((a[7] + b[7]) * inv) << 16);
    *(uint4*)&g.out[(size_t)node * 256 + c] = o;
}

// D=128: 512 threads, 32 nodes/block, 16 lanes per node (8 cols each).
__device__ __forceinline__ void gather128_body(const Gather128Job& g, int gb)
{
    const int node = gb * 32 + (threadIdx.x >> 4);
    const int c = (threadIdx.x & 15) * 8;
    if (node >= g.N) return;
    const int beg = g.rowptr[node];
    const int deg = g.cnt[node];
    const int end = beg + deg;
    const ushort_t* __restrict__ X = g.X;
    const int* __restrict__ col = g.col;
    float a[8] = {0, 0, 0, 0, 0, 0, 0, 0};
    float b[8] = {0, 0, 0, 0, 0, 0, 0, 0};
    int i = beg;
    for (; i + 3 < end; i += 4) {
        const int c0 = col[i], c1 = col[i + 1], c2 = col[i + 2], c3 = col[i + 3];
        uint4 v0 = *(const uint4*)&X[(size_t)c0 * 128 + c];
        uint4 v1 = *(const uint4*)&X[(size_t)c1 * 128 + c];
        uint4 v2 = *(const uint4*)&X[(size_t)c2 * 128 + c];
        uint4 v3 = *(const uint4*)&X[(size_t)c3 * 128 + c];
        UNPACK_ADD(a, v0) UNPACK_ADD(b, v1) UNPACK_ADD(a, v2) UNPACK_ADD(b, v3)
    }
    for (; i + 1 < end; i += 2) {
        uint4 v0 = *(const uint4*)&X[(size_t)col[i] * 128 + c];
        uint4 v1 = *(const uint4*)&X[(size_t)col[i + 1] * 128 + c];
        UNPACK_ADD(a, v0) UNPACK_ADD(b, v1)
    }
    if (i < end) {
        uint4 v0 = *(const uint4*)&X[(size_t)col[i] * 128 + c];
        UNPACK_ADD(a, v0)
    }
    float inv = 1.f / fmaxf((float)deg, 1.f);
    uint4 o;
    o.x = (unsigned int)f2bf((a[0] + b[0]) * inv) | ((unsigned int)f2bf((a[1] + b[1]) * inv) << 16);
    o.y = (unsigned int)f2bf((a[2] + b[2]) * inv) | ((unsigned int)f2bf((a[3] + b[3]) * inv) << 16);
    o.z = (unsigned int)f2bf((a[4] + b[4]) * inv) | ((unsigned int)f2bf((a[5] + b[5]) * inv) << 16);
    o.w = (unsigned int)f2bf((a[6] + b[6]) * inv) | ((unsigned int)f2bf((a[7] + b[7]) * inv) << 16);
    *(uint4*)&g.out[(size_t)node * 128 + c] = o;
}

// ---------------------- CSR-build device bodies ----------------------------
__device__ __forceinline__ void binA_body(
    const int* __restrict__ key, const int* __restrict__ val, int E,
    int nbins, int shift, int vbits,
    int* __restrict__ gcur, unsigned* __restrict__ stg, int ablk)
{
    __shared__ unsigned bins[NB_S * BIN_CAP];
    __shared__ int lcnt[NB_S], gbase[NB_S];
    const int tid = threadIdx.x;
    const int base = ablk * CHUNK;
    for (int i = tid; i < nbins; i += 256) lcnt[i] = 0;
    __syncthreads();
    const unsigned lowmask = (1u << shift) - 1u;
#pragma unroll
    for (int k = 0; k < CHUNK / 256; k++) {
        int e = base + k * 256 + tid;
        if (e < E) {
            int kk = key[e];
            int b = kk >> shift;
            unsigned pk = (((unsigned)kk & lowmask) << vbits) | (unsigned)val[e];
            int c = atomicAdd(&lcnt[b], 1);
            if (c < BIN_CAP) bins[b * BIN_CAP + c] = pk;
            else { int p = atomicAdd(&gcur[b], 1); stg[p] = pk; }
        }
    }
    __syncthreads();
    if (tid < nbins) gbase[tid] = atomicAdd(&gcur[tid], min(lcnt[tid], BIN_CAP));
    __syncthreads();
    for (int b = 0; b < nbins; b++) {
        int c = min(lcnt[b], BIN_CAP);
        for (int i = tid; i < c; i += 256) stg[gbase[b] + i] = bins[b * BIN_CAP + i];
    }
}

__device__ __forceinline__ void binB_body(
    const unsigned* __restrict__ stg, const int* __restrict__ rowptr,
    int N, int node_per, int vbits, int* __restrict__ colout, int bblk)
{
    __shared__ int cur[1024];
    const int tid = threadIdx.x;
    const int node0 = bblk * node_per;
    const int nn = min(node_per, N - node0);
    for (int i = tid; i < nn; i += 256) cur[i] = rowptr[node0 + i];
    const int estart = rowptr[node0];
    const int eend = rowptr[node0 + nn];
    __syncthreads();
    const unsigned vmask = (1u << vbits) - 1u;
    for (int i = estart + tid; i < eend; i += 256) {
        unsigned v = stg[i];
        int kl = (int)(v >> vbits);
        int pos = atomicAdd(&cur[kl], 1);
        colout[pos] = (int)(v & vmask);
    }
}

// ----------------------- ILP-4 fp32 -> bf16 convert ------------------------
struct CvtJobs {
    const float* src[14];
    ushort_t* dst[14];
    int n4[14];
    int cnt;
};

__device__ __forceinline__ void cvt_body(const CvtJobs& jb, int nchunks,
                                         int ch0, int stride)
{
    const int t = threadIdx.x;
#pragma unroll 1
    for (int ch = ch0; ch < nchunks; ch += stride) {
        int idx = ch << 10;                // first float4 of this chunk
        int k = 0;
        while (idx >= jb.n4[k]) { idx -= jb.n4[k]; ++k; }   // uniform search
        const float4* __restrict__ s = (const float4*)jb.src[k];
        ushort_t* __restrict__ d = jb.dst[k];
        const int base = idx + t;
        float4 v0 = s[base];
        float4 v1 = s[base + 256];
        float4 v2 = s[base + 512];
        float4 v3 = s[base + 768];
        uint2 o0, o1, o2, o3;
        o0.x = (unsigned int)f2bf(v0.x) | ((unsigned int)f2bf(v0.y) << 16);
        o0.y = (unsigned int)f2bf(v0.z) | ((unsigned int)f2bf(v0.w) << 16);
        o1.x = (unsigned int)f2bf(v1.x) | ((unsigned int)f2bf(v1.y) << 16);
        o1.y = (unsigned int)f2bf(v1.z) | ((unsigned int)f2bf(v1.w) << 16);
        o2.x = (unsigned int)f2bf(v2.x) | ((unsigned int)f2bf(v2.y) << 16);
        o2.y = (unsigned int)f2bf(v2.z) | ((unsigned int)f2bf(v2.w) << 16);
        o3.x = (unsigned int)f2bf(v3.x) | ((unsigned int)f2bf(v3.y) << 16);
        o3.y = (unsigned int)f2bf(v3.z) | ((unsigned int)f2bf(v3.w) << 16);
        *(uint2*)(d + (size_t)base * 4) = o0;
        *(uint2*)(d + (size_t)(base + 256) * 4) = o1;
        *(uint2*)(d + (size_t)(base + 512) * 4) = o2;
        *(uint2*)(d + (size_t)(base + 768) * 4) = o3;
    }
}

// -------------------- fold + count bodies ----------------------------------
__device__ __forceinline__ void fold_body(
    const float* __restrict__ Wd1, const float* __restrict__ bd1,
    const float* __restrict__ Wlin_s, const float* __restrict__ blin_s,
    const float* __restrict__ Wlin_t, const float* __restrict__ blin_t,
    float* __restrict__ Wc_s, float* __restrict__ Wc_t,
    float* __restrict__ bu, float* __restrict__ bv, int b)
{
    const int t = threadIdx.x;
    if (b < 256) {
        float s = 0.f;
        for (int k = 0; k < 256; k++) s += Wd1[b * 512 + k] * Wlin_s[k * 256 + t];
        Wc_s[b * 256 + t] = s;
    } else if (b < 512) {
        const int h = b - 256;
        float s = 0.f;
        for (int k = 0; k < 256; k++) s += Wd1[h * 512 + 256 + k] * Wlin_t[k * 256 + t];
        Wc_t[h * 256 + t] = s;
    } else {
        float su = 0.f, sv = 0.f;
        for (int k = 0; k < 256; k++) {
            su += Wd1[t * 512 + k] * blin_s[k];
            sv += Wd1[t * 512 + 256 + k] * blin_t[k];
        }
        bu[t] = bd1[t] + su;
        bv[t] = sv;
    }
}

__device__ __forceinline__ void count_body(
    const int* __restrict__ src, const int* __restrict__ dst,
    int* __restrict__ cnt_s, int* __restrict__ cnt_t, int E, int cblk)
{
    const int base = cblk * 1024 + threadIdx.x;
    const int e0 = base, e1 = base + 256, e2 = base + 512, e3 = base + 768;
    int s0 = 0, s1 = 0, s2 = 0, s3 = 0;
    int d0 = 0, d1 = 0, d2 = 0, d3 = 0;
    if (e0 < E) { s0 = src[e0]; d0 = dst[e0]; }
    if (e1 < E) { s1 = src[e1]; d1 = dst[e1]; }
    if (e2 < E) { s2 = src[e2]; d2 = dst[e2]; }
    if (e3 < E) { s3 = src[e3]; d3 = dst[e3]; }
    if (e0 < E) { atomicAdd(&cnt_s[s0], 1); atomicAdd(&cnt_t[d0], 1); }
    if (e1 < E) { atomicAdd(&cnt_s[s1], 1); atomicAdd(&cnt_t[d1], 1); }
    if (e2 < E) { atomicAdd(&cnt_s[s2], 1); atomicAdd(&cnt_t[d2], 1); }
    if (e3 < E) { atomicAdd(&cnt_s[s3], 1); atomicAdd(&cnt_t[d3], 1); }
}

// --------------------------- fused launch shells ---------------------------
__global__ __launch_bounds__(256) void gemm_gemm_kernel(GemmJob a, int ablocks,
                                                        GemmJob b)
{
    const int bid = blockIdx.x;
    if (bid < ablocks) gemm_body(a, bid);
    else gemm_body(b, bid - ablocks);
}

__global__ __launch_bounds__(512) void gather_g128_kernel(GatherJob a, int ablocks,
                                                          Gather128Job b)
{
    const int bid = blockIdx.x;
    if (bid < ablocks) gather_body(a, bid);
    else gather128_body(b, bid - ablocks);
}

__global__ __launch_bounds__(512) void gather_gather_kernel(GatherJob a, int ablocks,
                                                            GatherJob b)
{
    const int bid = blockIdx.x;
    if (bid < ablocks) gather_body(a, bid);
    else gather_body(b, bid - ablocks);
}

__global__ __launch_bounds__(256) void fold_count_kernel(
    const float* Wd1, const float* bd1,
    const float* Wlin_s, const float* blin_s,
    const float* Wlin_t, const float* blin_t,
    float* Wc_s, float* Wc_t, float* bu, float* bv,
    const int* src, const int* dst, int* cnt_s, int* cnt_t, int E)
{
    const int bid = blockIdx.x;
    if (bid < 513)
        fold_body(Wd1, bd1, Wlin_s, blin_s, Wlin_t, blin_t, Wc_s, Wc_t, bu, bv, bid);
    else
        count_body(src, dst, cnt_s, cnt_t, E, bid - 513);
}

__global__ __launch_bounds__(256) void cvt_binA_kernel(
    CvtJobs jb, int nchunks, int aBlocks,
    const int* key, const int* val, int E, int nbins, int shift, int vbits,
    int* gcur, unsigned* stg)
{
    const int bid = blockIdx.x;
    if (bid < aBlocks)
        binA_body(key, val, E, nbins, shift, vbits, gcur, stg, bid);
    else
        cvt_body(jb, nchunks, bid - aBlocks, gridDim.x - aBlocks);
}

__global__ __launch_bounds__(256) void binA_binB_kernel(
    const int* keyA, const int* valA, int E, int nbinsA, int shiftA, int vbitsA,
    int* gcurA, unsigned* stgA, int aBlocks,
    const unsigned* stgB, const int* rowptrB, int NB, int nodeperB, int vbitsB,
    int* coloutB)
{
    const int bid = blockIdx.x;
    if (bid < aBlocks)
        binA_body(keyA, valA, E, nbinsA, shiftA, vbitsA, gcurA, stgA, bid);
    else
        binB_body(stgB, rowptrB, NB, nodeperB, vbitsB, coloutB, bid - aBlocks);
}

__global__ __launch_bounds__(256) void binB_kernel(
    const unsigned* __restrict__ stg, const int* __restrict__ rowptr,
    int N, int node_per, int vbits, int* __restrict__ colout)
{
    binB_body(stg, rowptr, N, node_per, vbits, colout, blockIdx.x);
}

// --------------------------- CSR scan kernels ------------------------------
__global__ __launch_bounds__(256) void psum_kernel(
    const int* __restrict__ cnt_s, const int* __restrict__ cnt_t,
    int* __restrict__ bsum_s, int* __restrict__ bsum_t, int nbS)
{
    const bool isS = (int)blockIdx.x < nbS;
    const int blk = isS ? blockIdx.x : blockIdx.x - nbS;
    const int N = isS ? NS : NT;
    const int* cnt = isS ? cnt_s : cnt_t;
    int* bsum = isS ? bsum_s : bsum_t;
    __shared__ int sdata[256];
    const int t = threadIdx.x;
    const int base = blk * 1024;
    int s = 0;
    for (int i = t; i < 1024; i += 256) {
        int idx = base + i;
        s += (idx < N) ? cnt[idx] : 0;
    }
    sdata[t] = s; __syncthreads();
    for (int off = 128; off > 0; off >>= 1) {
        if (t < off) sdata[t] += sdata[t + off];
        __syncthreads();
    }
    if (t == 0) bsum[blk] = sdata[0];
}

__global__ void sbsum_kernel(int* __restrict__ bsum_s, int* __restrict__ bsum_t,
                             int nbS, int nbT)
{
    if (threadIdx.x != 0) return;
    int* b = blockIdx.x ? bsum_t : bsum_s;
    int nb = blockIdx.x ? nbT : nbS;
    int run = 0;
    for (int i = 0; i < nb; i++) { int v = b[i]; b[i] = run; run += v; }
}

__global__ __launch_bounds__(256) void sblock_kernel(
    const int* __restrict__ cnt_s, const int* __restrict__ cnt_t,
    const int* __restrict__ bsum_s, const int* __restrict__ bsum_t,
    int* __restrict__ rowptr_s, int* __restrict__ rowptr_t, int nbS)
{
    const bool isS = (int)blockIdx.x < nbS;
    const int blk = isS ? blockIdx.x : blockIdx.x - nbS;
    const int N = isS ? NS : NT;
    const int* cnt = isS ? cnt_s : cnt_t;
    const int* bsum = isS ? bsum_s : bsum_t;
    int* rowptr = isS ? rowptr_s : rowptr_t;
    __shared__ int sc[256];
    const int t = threadIdx.x;
    const int base = blk * 1024 + t * 4;
    int v[4]; int s = 0;
#pragma unroll
    for (int j = 0; j < 4; j++) {
        int idx = base + j;
        v[j] = (idx < N) ? cnt[idx] : 0;
        s += v[j];
    }
    sc[t] = s; __syncthreads();
    for (int off = 1; off < 256; off <<= 1) {
        int add = (t >= off) ? sc[t - off] : 0;
        __syncthreads();
        sc[t] += add;
        __syncthreads();
    }
    int excl = sc[t] - s + bsum[blk];
#pragma unroll
    for (int j = 0; j < 4; j++) {
        int idx = base + j;
        if (idx < N) rowptr[idx] = excl;
        if (idx == N - 1) rowptr[N] = excl + v[j];
        excl += v[j];
    }
}

__global__ void binit_kernel(const int* __restrict__ rowptr_t,
                             const int* __restrict__ rowptr_s,
                             int* __restrict__ gcur_t, int* __restrict__ gcur_s)
{
    int t = threadIdx.x;
    if (t < NB_T) gcur_t[t] = rowptr_t[t << SH_T];
    if (t < NB_S) gcur_s[t] = rowptr_s[t << SH_S];
}

// ------------------------- per-edge score (fp16 U/V) -----------------------
__global__ __launch_bounds__(256) void edge_score_kernel(
    const _Float16* __restrict__ U, const _Float16* __restrict__ V,
    const int* __restrict__ ls, const int* __restrict__ ld,
    const float* __restrict__ Wd2, const float* __restrict__ bd2,
    float* __restrict__ out, int EL)
{
    const int l32 = threadIdx.x & 31;
    const int e = blockIdx.x * 8 + (threadIdx.x >> 5);
    if (e >= EL) return;
    const int c = l32 * 8;
    half8v u = *(const half8v*)&U[(size_t)ls[e] * 256 + c];
    half8v v = *(const half8v*)&V[(size_t)ld[e] * 256 + c];
    float4 w0 = *(const float4*)&Wd2[c];
    float4 w1 = *(const float4*)&Wd2[c + 4];
    float s = fmaxf((float)u[0] + (float)v[0], 0.f) * w0.x
            + fmaxf((float)u[1] + (float)v[1], 0.f) * w0.y
            + fmaxf((float)u[2] + (float)v[2], 0.f) * w0.z
            + fmaxf((float)u[3] + (float)v[3], 0.f) * w0.w
            + fmaxf((float)u[4] + (float)v[4], 0.f) * w1.x
            + fmaxf((float)u[5] + (float)v[5], 0.f) * w1.y
            + fmaxf((float)u[6] + (float)v[6], 0.f) * w1.z
            + fmaxf((float)u[7] + (float)v[7], 0.f) * w1.w;
#pragma unroll
    for (int m = 16; m >= 1; m >>= 1) s += __shfl_xor(s, m, 64);
    if (l32 == 0) out[e] = s + bd2[0];
}

// ---------------------------------------------------------------------------
extern "C" void kernel_launch(void* const* d_in, const int* in_sizes, int n_in,
                              void* d_out, int out_size, void* d_ws, size_t ws_size,
                              hipStream_t stream)
{
    const float* x_sotu  = (const float*)d_in[0];
    const float* x_taxon = (const float*)d_in[1];
    const int* edge_src  = (const int*)d_in[2];
    const int* edge_dst  = (const int*)d_in[3];
    const int* label_src = (const int*)d_in[4];
    const int* label_dst = (const int*)d_in[5];
    const float* Wl1_st = (const float*)d_in[6];
    const float* bl1_st = (const float*)d_in[7];
    const float* Wr1_st = (const float*)d_in[8];
    const float* Wl1_ts = (const float*)d_in[9];
    const float* bl1_ts = (const float*)d_in[10];
    const float* Wr1_ts = (const float*)d_in[11];
    const float* Wl2_st = (const float*)d_in[12];
    const float* bl2_st = (const float*)d_in[13];
    const float* Wr2_st = (const float*)d_in[14];
    const float* Wl2_ts = (const float*)d_in[15];
    const float* bl2_ts = (const float*)d_in[16];
    const float* Wr2_ts = (const float*)d_in[17];
    const float* Wlin_s = (const float*)d_in[18];
    const float* blin_s = (const float*)d_in[19];
    const float* Wlin_t = (const float*)d_in[20];
    const float* blin_t = (const float*)d_in[21];
    const float* Wd1 = (const float*)d_in[22];
    const float* bd1 = (const float*)d_in[23];
    const float* Wd2 = (const float*)d_in[24];
    const float* bd2 = (const float*)d_in[25];

    // -------- workspace layout --------
    int* wi = (int*)d_ws;
    size_t io = 0;
    int* cnt_s   = wi + io; io += NS;
    int* cnt_t   = wi + io; io += NT;
    int* rowptr_s = wi + io; io += NS + 8;
    int* rowptr_t = wi + io; io += NT + 8;
    int* col_s   = wi + io; io += E_EDGES;
    int* col_t   = wi + io; io += E_EDGES;
    unsigned* stg_s = (unsigned*)(wi + io); io += E_EDGES;
    unsigned* stg_t = (unsigned*)(wi + io); io += E_EDGES;
    int* bsum_s  = wi + io; io += 128;
    int* bsum_t  = wi + io; io += 128;
    int* gcur_t  = wi + io; io += 128;
    int* gcur_s  = wi + io; io += 128;
    io = (io + 63) & ~(size_t)63;

    ushort_t* wb = (ushort_t*)(wi + io);
    size_t bo = 0;
    ushort_t* m_s  = wb + bo; bo += (size_t)NS * H;   // mxt/mh gather out; U overlays
    ushort_t* h1_s = wb + bo; bo += (size_t)NS * H;
    ushort_t* m_t  = wb + bo; bo += (size_t)NT * H;   // V (fp16) overlays m_t
    ushort_t* h1_t = wb + bo; bo += (size_t)NT * H;
    ushort_t* h2_s = wb + bo; bo += (size_t)NS * H;
    ushort_t* h2_t = wb + bo; bo += (size_t)NT * H;
    ushort_t* xs_b = wb + bo; bo += (size_t)NS * DS;
    ushort_t* xt_b = wb + bo; bo += (size_t)NT * DT;
    ushort_t* wb_l1st = wb + bo; bo += H * DS;
    ushort_t* wb_r1st = wb + bo; bo += H * DT;
    ushort_t* wb_l1ts = wb + bo; bo += H * DT;
    ushort_t* wb_r1ts = wb + bo; bo += H * DS;
    ushort_t* wb_l2st = wb + bo; bo += H * H;
    ushort_t* wb_r2st = wb + bo; bo += H * H;
    ushort_t* wb_l2ts = wb + bo; bo += H * H;
    ushort_t* wb_r2ts = wb + bo; bo += H * H;
    ushort_t* wcb_s   = wb + bo; bo += H * H;
    ushort_t* wcb_t   = wb + bo; bo += H * H;
    bo = (bo + 7) & ~(size_t)7;

    float* wf = (float*)(wb + bo);
    size_t fo = 0;
    float* Wc_s = wf + fo; fo += H * H;
    float* Wc_t = wf + fo; fo += H * H;
    float* bu   = wf + fo; fo += 256;
    float* bv   = wf + fo; fo += 256;

    _Float16* U = (_Float16*)m_s;
    _Float16* V = (_Float16*)m_t;

    const dim3 blk(256);
    const dim3 blk512(512);
    auto mgn = [](int M) { return ((M + 63) / 64) * 2; };     // gemm blocks (64-row)
    auto g256n = [](int N) { return (N + 15) / 16; };         // D=256 gather blocks
    auto g128n = [](int N) { return (N + 31) / 32; };         // D=128 gather blocks
    const int nbS = (NS + 1023) / 1024;   // 98
    const int nbT = (NT + 1023) / 1024;   // 20
    const int nA = (E_EDGES + CHUNK - 1) / CHUNK;   // 391
    const int cntBlocks = (E_EDGES + 1023) / 1024;  // 782

    // ---- [decoder weight folding || edge-degree count] ----
    hipMemsetAsync(cnt_s, 0, (size_t)(NS + NT) * sizeof(int), stream);
    fold_count_kernel<<<513 + cntBlocks, blk, 0, stream>>>(
        Wd1, bd1, Wlin_s, blin_s, Wlin_t, blin_t, Wc_s, Wc_t, bu, bv,
        edge_src, edge_dst, cnt_s, cnt_t, E_EDGES);

    // ---- CSR scan ----
    psum_kernel<<<nbS + nbT, blk, 0, stream>>>(cnt_s, cnt_t, bsum_s, bsum_t, nbS);
    sbsum_kernel<<<2, 64, 0, stream>>>(bsum_s, bsum_t, nbS, nbT);
    sblock_kernel<<<nbS + nbT, blk, 0, stream>>>(cnt_s, cnt_t, bsum_s, bsum_t,
                                                 rowptr_s, rowptr_t, nbS);
    binit_kernel<<<1, blk, 0, stream>>>(rowptr_t, rowptr_s, gcur_t, gcur_s);

    // ---- [binA_t || ILP-4 fp32->bf16 convert] ----
    {
        CvtJobs jb; int c = 0, total4 = 0;
        auto addj = [&](const float* s, ushort_t* d, int n) {
            jb.src[c] = s; jb.dst[c] = d; jb.n4[c] = n / 4; total4 += n / 4; c++;
        };
        addj(x_sotu, xs_b, NS * DS);
        addj(x_taxon, xt_b, NT * DT);
        addj(Wl1_st, wb_l1st, H * DS);
        addj(Wr1_st, wb_r1st, H * DT);
        addj(Wl1_ts, wb_l1ts, H * DT);
        addj(Wr1_ts, wb_r1ts, H * DS);
        addj(Wl2_st, wb_l2st, H * H);
        addj(Wr2_st, wb_r2st, H * H);
        addj(Wl2_ts, wb_l2ts, H * H);
        addj(Wr2_ts, wb_r2ts, H * H);
        addj(Wc_s, wcb_s, H * H);
        addj(Wc_t, wcb_t, H * H);
        jb.cnt = c;
        const int nchunks = total4 >> 10;  // every n4 is a multiple of 1024
        const int cvb = nchunks < CVT_BLOCKS ? nchunks : CVT_BLOCKS;
        cvt_binA_kernel<<<nA + cvb, blk, 0, stream>>>(
            jb, nchunks, nA,
            edge_dst, edge_src, E_EDGES, NB_T, SH_T, VB_T, gcur_t, stg_t);
    }

    // ---- [binA_s || binB_t] ----
    binA_binB_kernel<<<nA + NB_T, blk, 0, stream>>>(
        edge_src, edge_dst, E_EDGES, NB_S, SH_S, VB_S, gcur_s, stg_s, nA,
        stg_t, rowptr_t, NT, 1 << SH_T, VB_T, col_t);

    // ---- binB_s ----
    binB_kernel<<<NB_S, blk, 0, stream>>>(stg_s, rowptr_s, NS, 1 << SH_S, VB_S, col_s);

    // ---- layer 1: aggregate-then-project ----
    {   // m_t = gmean(xs) [D=256]  ||  mxt_s = gmean(xt) [D=128, in m_s slot]
        GatherJob a{xs_b, rowptr_t, cnt_t, col_t, m_t, NT};
        Gather128Job b{xt_b, rowptr_s, cnt_s, col_s, m_s, NS};
        const int ab = g256n(NT);
        gather_g128_kernel<<<ab + g128n(NS), blk512, 0, stream>>>(a, ab, b);
    }
    {   // h1_s = relu(xs@Wr1_ts' + mxt_s@Wl1_ts' + b)  ||  h1_t = relu(...)
        GemmJob a{xs_b, wb_r1ts, DS, m_s, wb_l1ts, DT, nullptr, bl1_ts, h1_s, NS, 1};
        GemmJob b{m_t, wb_l1st, H, xt_b, wb_r1st, DT, nullptr, bl1_st, h1_t, NT, 1};
        const int ab = mgn(NS);
        gemm_gemm_kernel<<<ab + mgn(NT), blk, 0, stream>>>(a, ab, b);
    }

    // ---- layer 2: aggregate-then-project ----
    {   // m_t = gmean(h1_s) [D=256]  ||  mh_s = gmean(h1_t) [D=256, m_s slot]
        GatherJob a{h1_s, rowptr_t, cnt_t, col_t, m_t, NT};
        GatherJob b{h1_t, rowptr_s, cnt_s, col_s, m_s, NS};
        const int ab = g256n(NT);
        gather_gather_kernel<<<ab + g256n(NS), blk512, 0, stream>>>(a, ab, b);
    }
    {   // h2_s = relu(h1_s@Wr2_ts' + mh_s@Wl2_ts' + b)  ||  h2_t = relu(...)
        GemmJob a{h1_s, wb_r2ts, H, m_s, wb_l2ts, H, nullptr, bl2_ts, h2_s, NS, 1};
        GemmJob b{m_t, wb_l2st, H, h1_t, wb_r2st, H, nullptr, bl2_st, h2_t, NT, 1};
        const int ab = mgn(NS);
        gemm_gemm_kernel<<<ab + mgn(NT), blk, 0, stream>>>(a, ab, b);
    }

    // ---- decoder: U (NS) || V (NT) node potentials (fp16 out) ----
    {
        GemmJob a{h2_s, wcb_s, H, nullptr, nullptr, 0, nullptr, bu, U, NS, 2};
        GemmJob b{h2_t, wcb_t, H, nullptr, nullptr, 0, nullptr, bv, V, NT, 2};
        const int ab = mgn(NS);
        gemm_gemm_kernel<<<ab + mgn(NT), blk, 0, stream>>>(a, ab, b);
    }
    edge_score_kernel<<<(EL_EDGES + 7) / 8, blk, 0, stream>>>(
        U, V, label_src, label_dst, Wd2, bd2, (float*)d_out, EL_EDGES);
}